// Round 1
// baseline (629.464 us; speedup 1.0000x reference)
//
#include <hip/hip_runtime.h>
#include <math.h>

// ---------------------------------------------------------------------------
// CrossAttentionGNNConv: N=50000 nodes, E=800000 edges, D=64
//   qa = t_tgt@Qa_W.T+Qa_b ; ka = t_src@Ka_W.T+Ka_b ; vt = t_src@W_t.T
//   qb = x_tgt@Qb_W.T+Qb_b ; kb = x_src@Kb_W.T+Kb_b ; vx = x_src@W_x.T
//   alpha = segment_softmax(dot(qa[row],ka[col])/8, row)
//   beta  = segment_softmax(dot(qb[row],kb[col])/8, row)
//   out_t[n] = sum_{e: row=n} alpha_e * vt[col_e]   (out_x analogous with beta,vx)
// Strategy: CSR by row (no float atomics), one wave per destination node.
// ---------------------------------------------------------------------------

#define D 64

// --- edge_index dtype detection (int32 vs int64) ---------------------------
__global__ void detect_idx64(const unsigned long long* __restrict__ ei,
                             int* __restrict__ flag, int nCheck,
                             unsigned long long nNodes) {
  if (blockIdx.x == 0 && threadIdx.x == 0) {
    int is64 = 1;
    for (int i = 0; i < nCheck; ++i) {
      if (ei[i] >= nNodes) { is64 = 0; break; }
    }
    *flag = is64;
  }
}

__global__ void zero_ints(int* __restrict__ p, int n) {
  int i = blockIdx.x * blockDim.x + threadIdx.x;
  if (i < n) p[i] = 0;
}

// --- CSR build -------------------------------------------------------------
__global__ void edge_degree(const void* __restrict__ ei, const int* __restrict__ flag,
                            int* __restrict__ deg, int E) {
  int e = blockIdx.x * blockDim.x + threadIdx.x;
  if (e >= E) return;
  int r = (*flag) ? (int)((const long long*)ei)[e] : ((const int*)ei)[e];
  atomicAdd(&deg[r], 1);
}

__global__ void scan_block_sums(const int* __restrict__ deg, int* __restrict__ bsum, int N) {
  __shared__ int sdata[256];
  int i = blockIdx.x * 256 + threadIdx.x;
  sdata[threadIdx.x] = (i < N) ? deg[i] : 0;
  __syncthreads();
  for (int s = 128; s > 0; s >>= 1) {
    if (threadIdx.x < s) sdata[threadIdx.x] += sdata[threadIdx.x + s];
    __syncthreads();
  }
  if (threadIdx.x == 0) bsum[blockIdx.x] = sdata[0];
}

// single block; nB <= 256; in-place exclusive scan
__global__ void scan_exclusive_small(int* __restrict__ bsum, int nB) {
  __shared__ int sdata[256];
  int t = threadIdx.x;
  int v = (t < nB) ? bsum[t] : 0;
  sdata[t] = v;
  __syncthreads();
  for (int off = 1; off < 256; off <<= 1) {
    int add = (t >= off) ? sdata[t - off] : 0;
    __syncthreads();
    sdata[t] += add;
    __syncthreads();
  }
  if (t < nB) bsum[t] = sdata[t] - v;
}

__global__ void scan_finalize(const int* __restrict__ deg, const int* __restrict__ bsum,
                              int* __restrict__ offs, int* __restrict__ cursor,
                              int N, int E) {
  __shared__ int sdata[256];
  int t = threadIdx.x;
  int i = blockIdx.x * 256 + t;
  int v = (i < N) ? deg[i] : 0;
  sdata[t] = v;
  __syncthreads();
  for (int off = 1; off < 256; off <<= 1) {
    int add = (t >= off) ? sdata[t - off] : 0;
    __syncthreads();
    sdata[t] += add;
    __syncthreads();
  }
  int excl = sdata[t] - v + bsum[blockIdx.x];
  if (i < N) { offs[i] = excl; cursor[i] = excl; }
  if (blockIdx.x == 0 && t == 0) offs[N] = E;
}

__global__ void scatter_edges(const void* __restrict__ ei, const int* __restrict__ flag,
                              int* __restrict__ cursor, int* __restrict__ ecol, int E) {
  int e = blockIdx.x * blockDim.x + threadIdx.x;
  if (e >= E) return;
  int r, c;
  if (*flag) {
    const long long* p = (const long long*)ei;
    r = (int)p[e]; c = (int)p[(long long)E + e];
  } else {
    const int* p = (const int*)ei;
    r = p[e]; c = p[E + e];
  }
  int pos = atomicAdd(&cursor[r], 1);
  ecol[pos] = c;
}

// --- node projections: Y = X @ W.T (+ b). One wave per node row. ----------
// W rows register-cached per lane (lane j holds W[j][0..63]); x row read as
// uniform float4 broadcasts (all lanes same address -> single 16B request).
template <bool DUAL>
__global__ __launch_bounds__(256) void proj_kernel(
    const float* __restrict__ X,
    const float* __restrict__ W1, const float* __restrict__ b1, float* __restrict__ Y1,
    const float* __restrict__ W2, float* __restrict__ Y2, int nNodes) {
  const int lane = threadIdx.x & 63;
  const int gw = (blockIdx.x * blockDim.x + threadIdx.x) >> 6;
  const int nw = (gridDim.x * blockDim.x) >> 6;
  float w1r[D];
  float w2r[DUAL ? D : 1];
#pragma unroll
  for (int k4 = 0; k4 < D / 4; ++k4) {
    float4 v = ((const float4*)(W1 + (size_t)lane * D))[k4];
    w1r[4 * k4 + 0] = v.x; w1r[4 * k4 + 1] = v.y;
    w1r[4 * k4 + 2] = v.z; w1r[4 * k4 + 3] = v.w;
    if (DUAL) {
      float4 u = ((const float4*)(W2 + (size_t)lane * D))[k4];
      w2r[4 * k4 + 0] = u.x; w2r[4 * k4 + 1] = u.y;
      w2r[4 * k4 + 2] = u.z; w2r[4 * k4 + 3] = u.w;
    }
  }
  const float bias = (b1 != nullptr) ? b1[lane] : 0.0f;
  for (int n = gw; n < nNodes; n += nw) {
    const float4* xr = (const float4*)(X + (size_t)n * D);
    float a1 = bias, a2 = 0.0f;
#pragma unroll
    for (int k4 = 0; k4 < D / 4; ++k4) {
      float4 xv = xr[k4];
      a1 = fmaf(xv.x, w1r[4 * k4 + 0], a1);
      a1 = fmaf(xv.y, w1r[4 * k4 + 1], a1);
      a1 = fmaf(xv.z, w1r[4 * k4 + 2], a1);
      a1 = fmaf(xv.w, w1r[4 * k4 + 3], a1);
      if (DUAL) {
        a2 = fmaf(xv.x, w2r[4 * k4 + 0], a2);
        a2 = fmaf(xv.y, w2r[4 * k4 + 1], a2);
        a2 = fmaf(xv.z, w2r[4 * k4 + 2], a2);
        a2 = fmaf(xv.w, w2r[4 * k4 + 3], a2);
      }
    }
    Y1[(size_t)n * D + lane] = a1;
    if (DUAL) Y2[(size_t)n * D + lane] = a2;
  }
}

// --- main per-node attention + aggregation. One wave per destination node. -
#define CAP 80  // per-wave LDS score cache; larger degrees take recompute path

__global__ __launch_bounds__(256) void node_attn(
    const float* __restrict__ qa, const float* __restrict__ ka,
    const float* __restrict__ qb, const float* __restrict__ kb,
    const float* __restrict__ vt, const float* __restrict__ vx,
    const int* __restrict__ offs, const int* __restrict__ ecol,
    float* __restrict__ out_x, float* __restrict__ out_t, int nNodes) {
  __shared__ float s_sa[4][CAP];
  __shared__ float s_sb[4][CAP];
  __shared__ int s_c[4][CAP];
  const int lane = threadIdx.x & 63;
  const int wid = threadIdx.x >> 6;
  const int gw = (blockIdx.x * blockDim.x + threadIdx.x) >> 6;
  const int nw = (gridDim.x * blockDim.x) >> 6;
  const float scale = 0.125f;  // 1/sqrt(64)

  for (int n = gw; n < nNodes; n += nw) {
    const int s = offs[n];
    const int e = offs[n + 1];
    const int deg = e - s;
    const bool cached = (deg <= CAP);
    const float ql_a = qa[(size_t)n * D + lane];
    const float ql_b = qb[(size_t)n * D + lane];

    float ma = -3.4e38f, mb = -3.4e38f;
    float da = 0.0f, db = 0.0f;
    for (int i = s; i < e; ++i) {
      const int c = ecol[i];
      float va = ql_a * ka[(size_t)c * D + lane];
      float vb = ql_b * kb[(size_t)c * D + lane];
#pragma unroll
      for (int off = 32; off > 0; off >>= 1) {
        va += __shfl_xor(va, off);
        vb += __shfl_xor(vb, off);
      }
      va *= scale;
      vb *= scale;
      if (cached && lane == 0) {
        s_sa[wid][i - s] = va;
        s_sb[wid][i - s] = vb;
        s_c[wid][i - s] = c;
      }
      // online softmax (values are wave-uniform after butterfly reduce)
      float na = fmaxf(ma, va);
      da = da * __expf(ma - na) + __expf(va - na);
      ma = na;
      float nb = fmaxf(mb, vb);
      db = db * __expf(mb - nb) + __expf(vb - nb);
      mb = nb;
    }
    const float inv_da = (deg > 0) ? 1.0f / da : 0.0f;
    const float inv_db = (deg > 0) ? 1.0f / db : 0.0f;

    float acc_t = 0.0f, acc_x = 0.0f;
    for (int i = s; i < e; ++i) {
      int c;
      float sa_v, sb_v;
      if (cached) {
        c = s_c[wid][i - s];
        sa_v = s_sa[wid][i - s];
        sb_v = s_sb[wid][i - s];
      } else {
        c = ecol[i];
        float va = ql_a * ka[(size_t)c * D + lane];
        float vb = ql_b * kb[(size_t)c * D + lane];
#pragma unroll
        for (int off = 32; off > 0; off >>= 1) {
          va += __shfl_xor(va, off);
          vb += __shfl_xor(vb, off);
        }
        sa_v = va * scale;
        sb_v = vb * scale;
      }
      const float alpha = __expf(sa_v - ma) * inv_da;
      const float beta = __expf(sb_v - mb) * inv_db;
      acc_t = fmaf(alpha, vt[(size_t)c * D + lane], acc_t);
      acc_x = fmaf(beta, vx[(size_t)c * D + lane], acc_x);
    }
    out_x[(size_t)n * D + lane] = acc_x;
    out_t[(size_t)n * D + lane] = acc_t;
  }
}

// ---------------------------------------------------------------------------
extern "C" void kernel_launch(void* const* d_in, const int* in_sizes, int n_in,
                              void* d_out, int out_size, void* d_ws, size_t ws_size,
                              hipStream_t stream) {
  const float* x_src = (const float*)d_in[0];
  const float* x_tgt = (const float*)d_in[1];
  const float* t_src = (const float*)d_in[2];
  const float* t_tgt = (const float*)d_in[3];
  const void* edge_index = d_in[4];
  const float* W_x = (const float*)d_in[5];
  const float* W_t = (const float*)d_in[6];
  const float* Ka_W = (const float*)d_in[7];
  const float* Ka_b = (const float*)d_in[8];
  const float* Qa_W = (const float*)d_in[9];
  const float* Qa_b = (const float*)d_in[10];
  const float* Kb_W = (const float*)d_in[11];
  const float* Kb_b = (const float*)d_in[12];
  const float* Qb_W = (const float*)d_in[13];
  const float* Qb_b = (const float*)d_in[14];

  const int N = in_sizes[0] / D;
  const int E = in_sizes[4] / 2;
  const int nB = (N + 255) / 256;  // must be <= 256 (N <= 65536)

  // workspace carve (256B aligned regions)
  char* ws = (char*)d_ws;
  size_t ofs = 0;
  auto carve = [&](size_t bytes) {
    size_t p = ofs;
    ofs += (bytes + 255) & ~(size_t)255;
    return p;
  };
  float* qa = (float*)(ws + carve((size_t)N * D * 4));
  float* ka = (float*)(ws + carve((size_t)N * D * 4));
  float* qb = (float*)(ws + carve((size_t)N * D * 4));
  float* kb = (float*)(ws + carve((size_t)N * D * 4));
  float* vt = (float*)(ws + carve((size_t)N * D * 4));
  float* vx = (float*)(ws + carve((size_t)N * D * 4));
  int* offs = (int*)(ws + carve(((size_t)N + 1) * 4));
  int* deg = (int*)(ws + carve((size_t)N * 4));
  int* cursor = (int*)(ws + carve((size_t)N * 4));
  int* bsum = (int*)(ws + carve((size_t)nB * 4));
  int* ecol = (int*)(ws + carve((size_t)E * 4));
  int* flag = (int*)(ws + carve(4));
  (void)ws_size;

  float* out_x = (float*)d_out;
  float* out_t = out_x + (size_t)N * D;

  const int eBlocks = (E + 255) / 256;

  detect_idx64<<<1, 1, 0, stream>>>((const unsigned long long*)edge_index, flag, 16,
                                    (unsigned long long)N);
  zero_ints<<<(N + 255) / 256, 256, 0, stream>>>(deg, N);
  edge_degree<<<eBlocks, 256, 0, stream>>>(edge_index, flag, deg, E);
  scan_block_sums<<<nB, 256, 0, stream>>>(deg, bsum, N);
  scan_exclusive_small<<<1, 256, 0, stream>>>(bsum, nB);
  scan_finalize<<<nB, 256, 0, stream>>>(deg, bsum, offs, cursor, N, E);
  scatter_edges<<<eBlocks, 256, 0, stream>>>(edge_index, flag, cursor, ecol, E);

  proj_kernel<false><<<1024, 256, 0, stream>>>(t_tgt, Qa_W, Qa_b, qa, nullptr, nullptr, N);
  proj_kernel<true><<<1024, 256, 0, stream>>>(t_src, Ka_W, Ka_b, ka, W_t, vt, N);
  proj_kernel<false><<<1024, 256, 0, stream>>>(x_tgt, Qb_W, Qb_b, qb, nullptr, nullptr, N);
  proj_kernel<true><<<1024, 256, 0, stream>>>(x_src, Kb_W, Kb_b, kb, W_x, vx, N);

  node_attn<<<(N + 3) / 4, 256, 0, stream>>>(qa, ka, qb, kb, vt, vx, offs, ecol,
                                             out_x, out_t, N);
}

// Round 2
// 523.201 us; speedup vs baseline: 1.2031x; 1.2031x over previous
//
#include <hip/hip_runtime.h>
#include <math.h>

// ---------------------------------------------------------------------------
// CrossAttentionGNNConv: N=50000, E=800000, D=64
// CSR by destination row -> per-wave node attention.
// K/V arrays (ka,kb,vt,vx) stored bf16 (halves gather bytes); fp32 math.
// ---------------------------------------------------------------------------

#define D 64
#define CAP 96
#define NINF -3.0e38f
typedef unsigned short ushortT;

__device__ __forceinline__ float b2f(ushortT h) {
  return __uint_as_float(((unsigned)h) << 16);
}
__device__ __forceinline__ ushortT f2b(float f) {
  unsigned u = __float_as_uint(f);
  u += 0x7fffu + ((u >> 16) & 1u);
  return (ushortT)(u >> 16);
}

// --- edge_index dtype detection (int32 vs int64) ---------------------------
__global__ void detect_idx64(const unsigned long long* __restrict__ ei,
                             int* __restrict__ flag, int nCheck,
                             unsigned long long nNodes) {
  if (blockIdx.x == 0 && threadIdx.x == 0) {
    int is64 = 1;
    for (int i = 0; i < nCheck; ++i)
      if (ei[i] >= nNodes) { is64 = 0; break; }
    *flag = is64;
  }
}

// --- CSR build -------------------------------------------------------------
__global__ void edge_degree(const void* __restrict__ ei, const int* __restrict__ flag,
                            int* __restrict__ deg, int E) {
  int base = (blockIdx.x * blockDim.x + threadIdx.x) << 2;
  if (base >= E) return;
  const bool is64 = (*flag) != 0;
  if (base + 4 <= E) {
    int r0, r1, r2, r3;
    if (is64) {
      const long long* p = (const long long*)ei;
      r0 = (int)p[base]; r1 = (int)p[base + 1];
      r2 = (int)p[base + 2]; r3 = (int)p[base + 3];
    } else {
      const int* p = (const int*)ei;
      r0 = p[base]; r1 = p[base + 1]; r2 = p[base + 2]; r3 = p[base + 3];
    }
    atomicAdd(&deg[r0], 1); atomicAdd(&deg[r1], 1);
    atomicAdd(&deg[r2], 1); atomicAdd(&deg[r3], 1);
  } else {
    for (int j = base; j < E; ++j) {
      int r = is64 ? (int)((const long long*)ei)[j] : ((const int*)ei)[j];
      atomicAdd(&deg[r], 1);
    }
  }
}

__global__ void scan_block_sums(const int* __restrict__ deg, int* __restrict__ bsum, int N) {
  __shared__ int sdata[256];
  int i = blockIdx.x * 256 + threadIdx.x;
  sdata[threadIdx.x] = (i < N) ? deg[i] : 0;
  __syncthreads();
  for (int s = 128; s > 0; s >>= 1) {
    if (threadIdx.x < s) sdata[threadIdx.x] += sdata[threadIdx.x + s];
    __syncthreads();
  }
  if (threadIdx.x == 0) bsum[blockIdx.x] = sdata[0];
}

__global__ void scan_exclusive_small(int* __restrict__ bsum, int nB) {
  __shared__ int sdata[256];
  int t = threadIdx.x;
  int v = (t < nB) ? bsum[t] : 0;
  sdata[t] = v;
  __syncthreads();
  for (int off = 1; off < 256; off <<= 1) {
    int add = (t >= off) ? sdata[t - off] : 0;
    __syncthreads();
    sdata[t] += add;
    __syncthreads();
  }
  if (t < nB) bsum[t] = sdata[t] - v;
}

__global__ void scan_finalize(const int* __restrict__ deg, const int* __restrict__ bsum,
                              int* __restrict__ offs, int* __restrict__ cursor,
                              int N, int E) {
  __shared__ int sdata[256];
  int t = threadIdx.x;
  int i = blockIdx.x * 256 + t;
  int v = (i < N) ? deg[i] : 0;
  sdata[t] = v;
  __syncthreads();
  for (int off = 1; off < 256; off <<= 1) {
    int add = (t >= off) ? sdata[t - off] : 0;
    __syncthreads();
    sdata[t] += add;
    __syncthreads();
  }
  int excl = sdata[t] - v + bsum[blockIdx.x];
  if (i < N) { offs[i] = excl; cursor[i] = excl; }
  if (blockIdx.x == 0 && t == 0) offs[N] = E;
}

__global__ void scatter_edges(const void* __restrict__ ei, const int* __restrict__ flag,
                              int* __restrict__ cursor, int* __restrict__ ecol, int E) {
  int base = (blockIdx.x * blockDim.x + threadIdx.x) << 2;
  if (base >= E) return;
  const bool is64 = (*flag) != 0;
  int m = E - base; if (m > 4) m = 4;
  if (is64) {
    const long long* p = (const long long*)ei;
    for (int j = 0; j < m; ++j) {
      int r = (int)p[base + j];
      int c = (int)p[(long long)E + base + j];
      int pos = atomicAdd(&cursor[r], 1);
      ecol[pos] = c;
    }
  } else {
    const int* p = (const int*)ei;
    for (int j = 0; j < m; ++j) {
      int r = p[base + j];
      int c = p[E + base + j];
      int pos = atomicAdd(&cursor[r], 1);
      ecol[pos] = c;
    }
  }
}

// --- projections -----------------------------------------------------------
// W staged via LDS (coalesced global reads), then register-cached per lane
// (lane o holds W[o][0..63]); x row read as wave-uniform float4 broadcasts.
// LDS row stride 68 floats: 16B-aligned rows, bank = 4*(o+k) -> no extra
// conflict beyond inherent b128 cost.

__global__ __launch_bounds__(256) void proj_single(
    const float* __restrict__ X0, const float* __restrict__ Wm0,
    const float* __restrict__ bv0, float* __restrict__ Y0,
    const float* __restrict__ X1, const float* __restrict__ Wm1,
    const float* __restrict__ bv1, float* __restrict__ Y1,
    int nNodes, int blocksPerJob) {
  __shared__ float wl[64 * 68];
  const int job = blockIdx.x / blocksPerJob;
  const int jb = blockIdx.x % blocksPerJob;
  const float* X = job ? X1 : X0;
  const float* Wm = job ? Wm1 : Wm0;
  const float* bv = job ? bv1 : bv0;
  float* Y = job ? Y1 : Y0;
  const int tid = threadIdx.x;
#pragma unroll
  for (int j = 0; j < 4; ++j) {
    int i4 = tid + 256 * j;
    int o = i4 >> 4, k4 = i4 & 15;
    float4 v = ((const float4*)Wm)[i4];
    *(float4*)&wl[o * 68 + k4 * 4] = v;
  }
  __syncthreads();
  const int lane = tid & 63, wid = tid >> 6;
  float wr[64];
#pragma unroll
  for (int k4 = 0; k4 < 16; ++k4) {
    float4 v = *(const float4*)&wl[lane * 68 + k4 * 4];
    wr[4 * k4] = v.x; wr[4 * k4 + 1] = v.y; wr[4 * k4 + 2] = v.z; wr[4 * k4 + 3] = v.w;
  }
  const float bias = bv[lane];
  const int wj = jb * 4 + wid;
  const int nwj = blocksPerJob * 4;
  for (int n = wj; n < nNodes; n += nwj) {
    const float4* xr = (const float4*)(X + (size_t)n * D);
    float a0 = bias, a1 = 0.f;
#pragma unroll
    for (int k4 = 0; k4 < 8; ++k4) {
      float4 xv = xr[k4];
      a0 = fmaf(xv.x, wr[4 * k4 + 0], a0);
      a0 = fmaf(xv.y, wr[4 * k4 + 1], a0);
      a0 = fmaf(xv.z, wr[4 * k4 + 2], a0);
      a0 = fmaf(xv.w, wr[4 * k4 + 3], a0);
      float4 yv = xr[k4 + 8];
      a1 = fmaf(yv.x, wr[4 * k4 + 32], a1);
      a1 = fmaf(yv.y, wr[4 * k4 + 33], a1);
      a1 = fmaf(yv.z, wr[4 * k4 + 34], a1);
      a1 = fmaf(yv.w, wr[4 * k4 + 35], a1);
    }
    Y[(size_t)n * D + lane] = a0 + a1;
  }
}

__global__ __launch_bounds__(256) void proj_dual(
    const float* __restrict__ X0, const float* __restrict__ Wk0,
    const float* __restrict__ bk0, const float* __restrict__ Wv0,
    ushortT* __restrict__ K0, ushortT* __restrict__ V0,
    const float* __restrict__ X1, const float* __restrict__ Wk1,
    const float* __restrict__ bk1, const float* __restrict__ Wv1,
    ushortT* __restrict__ K1, ushortT* __restrict__ V1,
    int nNodes, int blocksPerJob) {
  __shared__ float wl[2][64 * 68];
  const int job = blockIdx.x / blocksPerJob;
  const int jb = blockIdx.x % blocksPerJob;
  const float* X = job ? X1 : X0;
  const float* Wk = job ? Wk1 : Wk0;
  const float* bk = job ? bk1 : bk0;
  const float* Wv = job ? Wv1 : Wv0;
  ushortT* K = job ? K1 : K0;
  ushortT* V = job ? V1 : V0;
  const int tid = threadIdx.x;
#pragma unroll
  for (int j = 0; j < 4; ++j) {
    int i4 = tid + 256 * j;
    int o = i4 >> 4, k4 = i4 & 15;
    float4 v = ((const float4*)Wk)[i4];
    *(float4*)&wl[0][o * 68 + k4 * 4] = v;
    float4 u = ((const float4*)Wv)[i4];
    *(float4*)&wl[1][o * 68 + k4 * 4] = u;
  }
  __syncthreads();
  const int lane = tid & 63, wid = tid >> 6;
  float w1r[64], w2r[64];
#pragma unroll
  for (int k4 = 0; k4 < 16; ++k4) {
    float4 v = *(const float4*)&wl[0][lane * 68 + k4 * 4];
    w1r[4 * k4] = v.x; w1r[4 * k4 + 1] = v.y; w1r[4 * k4 + 2] = v.z; w1r[4 * k4 + 3] = v.w;
    float4 u = *(const float4*)&wl[1][lane * 68 + k4 * 4];
    w2r[4 * k4] = u.x; w2r[4 * k4 + 1] = u.y; w2r[4 * k4 + 2] = u.z; w2r[4 * k4 + 3] = u.w;
  }
  const float bias = bk[lane];
  const int wj = jb * 4 + wid;
  const int nwj = blocksPerJob * 4;
  for (int n = wj; n < nNodes; n += nwj) {
    const float4* xr = (const float4*)(X + (size_t)n * D);
    float a0 = bias, a1 = 0.f, c0 = 0.f, c1 = 0.f;
#pragma unroll
    for (int k4 = 0; k4 < 8; ++k4) {
      float4 xv = xr[k4];
      a0 = fmaf(xv.x, w1r[4 * k4 + 0], a0);
      a0 = fmaf(xv.y, w1r[4 * k4 + 1], a0);
      a0 = fmaf(xv.z, w1r[4 * k4 + 2], a0);
      a0 = fmaf(xv.w, w1r[4 * k4 + 3], a0);
      c0 = fmaf(xv.x, w2r[4 * k4 + 0], c0);
      c0 = fmaf(xv.y, w2r[4 * k4 + 1], c0);
      c0 = fmaf(xv.z, w2r[4 * k4 + 2], c0);
      c0 = fmaf(xv.w, w2r[4 * k4 + 3], c0);
      float4 yv = xr[k4 + 8];
      a1 = fmaf(yv.x, w1r[4 * k4 + 32], a1);
      a1 = fmaf(yv.y, w1r[4 * k4 + 33], a1);
      a1 = fmaf(yv.z, w1r[4 * k4 + 34], a1);
      a1 = fmaf(yv.w, w1r[4 * k4 + 35], a1);
      c1 = fmaf(yv.x, w2r[4 * k4 + 32], c1);
      c1 = fmaf(yv.y, w2r[4 * k4 + 33], c1);
      c1 = fmaf(yv.z, w2r[4 * k4 + 34], c1);
      c1 = fmaf(yv.w, w2r[4 * k4 + 35], c1);
    }
    K[(size_t)n * D + lane] = f2b(a0 + a1);
    V[(size_t)n * D + lane] = f2b(c0 + c1);
  }
}

// --- per-node attention + aggregation, one wave per destination node -------
__global__ __launch_bounds__(256) void node_attn(
    const float* __restrict__ qa, const float* __restrict__ qb,
    const ushortT* __restrict__ ka, const ushortT* __restrict__ kb,
    const ushortT* __restrict__ vt, const ushortT* __restrict__ vx,
    const int* __restrict__ offs, const int* __restrict__ ecol,
    float* __restrict__ out_x, float* __restrict__ out_t, int nNodes) {
  __shared__ float s_wa[4][CAP];
  __shared__ float s_wb[4][CAP];
  const int lane = threadIdx.x & 63;
  const int wid = threadIdx.x >> 6;
  const int sub = lane >> 4;   // subgroup 0..3 (edge within chunk)
  const int sl = lane & 15;    // sublane within 16
  const int gw = (blockIdx.x * blockDim.x + threadIdx.x) >> 6;
  const int nw = (gridDim.x * blockDim.x) >> 6;
  const float scale = 0.125f;

  for (int n = gw; n < nNodes; n += nw) {
    const int s = offs[n], e = offs[n + 1], deg = e - s;
    const size_t nb = (size_t)n * D;
    if (deg == 0) {
      out_x[nb + lane] = 0.f;
      out_t[nb + lane] = 0.f;
      continue;
    }
    float acc_t = 0.f, acc_x = 0.f;
    if (deg <= CAP) {
      const float4 q4a = *(const float4*)(qa + nb + sl * 4);
      const float4 q4b = *(const float4*)(qb + nb + sl * 4);
      // Phase A: scores, 4 edges per pass (16 lanes each)
      for (int i = 0; i < deg; i += 4) {
        const int idx = i + sub;
        const int c = ecol[s + (idx < deg ? idx : 0)];
        const size_t cb = (size_t)c * D + sl * 4;
        ushort4 ha = *(const ushort4*)(ka + cb);
        ushort4 hb = *(const ushort4*)(kb + cb);
        float va = q4a.x * b2f(ha.x);
        va = fmaf(q4a.y, b2f(ha.y), va);
        va = fmaf(q4a.z, b2f(ha.z), va);
        va = fmaf(q4a.w, b2f(ha.w), va);
        float vb = q4b.x * b2f(hb.x);
        vb = fmaf(q4b.y, b2f(hb.y), vb);
        vb = fmaf(q4b.z, b2f(hb.z), vb);
        vb = fmaf(q4b.w, b2f(hb.w), vb);
#pragma unroll
        for (int off = 1; off < 16; off <<= 1) {
          va += __shfl_xor(va, off);
          vb += __shfl_xor(vb, off);
        }
        if (sl == 0 && idx < deg) {
          s_wa[wid][idx] = va * scale;
          s_wb[wid][idx] = vb * scale;
        }
      }
      // Phase B: parallel softmax (deg <= 96)
      float sa0 = (lane < deg) ? s_wa[wid][lane] : NINF;
      float sb0 = (lane < deg) ? s_wb[wid][lane] : NINF;
      float sa1 = (lane + 64 < deg) ? s_wa[wid][lane + 64] : NINF;
      float sb1 = (lane + 64 < deg) ? s_wb[wid][lane + 64] : NINF;
      float ma = fmaxf(sa0, sa1), mb = fmaxf(sb0, sb1);
#pragma unroll
      for (int off = 1; off < 64; off <<= 1) {
        ma = fmaxf(ma, __shfl_xor(ma, off));
        mb = fmaxf(mb, __shfl_xor(mb, off));
      }
      float ea0 = __expf(sa0 - ma), ea1 = __expf(sa1 - ma);
      float eb0 = __expf(sb0 - mb), eb1 = __expf(sb1 - mb);
      float da = ea0 + ea1, db = eb0 + eb1;
#pragma unroll
      for (int off = 1; off < 64; off <<= 1) {
        da += __shfl_xor(da, off);
        db += __shfl_xor(db, off);
      }
      const float ia = 1.0f / da, ib = 1.0f / db;
      if (lane < deg) { s_wa[wid][lane] = ea0 * ia; s_wb[wid][lane] = eb0 * ib; }
      if (lane + 64 < deg) { s_wa[wid][lane + 64] = ea1 * ia; s_wb[wid][lane + 64] = eb1 * ib; }
      // Phase C: aggregation (coalesced 64-lane gathers, 2-edge unroll)
      int i = 0;
      for (; i + 2 <= deg; i += 2) {
        int c0 = ecol[s + i], c1 = ecol[s + i + 1];
        float wa0 = s_wa[wid][i], wa1 = s_wa[wid][i + 1];
        float wb0 = s_wb[wid][i], wb1 = s_wb[wid][i + 1];
        float t0 = b2f(vt[(size_t)c0 * D + lane]);
        float x0 = b2f(vx[(size_t)c0 * D + lane]);
        float t1 = b2f(vt[(size_t)c1 * D + lane]);
        float x1 = b2f(vx[(size_t)c1 * D + lane]);
        acc_t = fmaf(wa0, t0, acc_t);
        acc_t = fmaf(wa1, t1, acc_t);
        acc_x = fmaf(wb0, x0, acc_x);
        acc_x = fmaf(wb1, x1, acc_x);
      }
      if (i < deg) {
        int c0 = ecol[s + i];
        acc_t = fmaf(s_wa[wid][i], b2f(vt[(size_t)c0 * D + lane]), acc_t);
        acc_x = fmaf(s_wb[wid][i], b2f(vx[(size_t)c0 * D + lane]), acc_x);
      }
    } else {
      // rare fallback: serial full-wave online softmax + recompute
      const float ql_a = qa[nb + lane];
      const float ql_b = qb[nb + lane];
      float ma = NINF, mb = NINF, da = 0.f, db = 0.f;
      for (int i = s; i < e; ++i) {
        int c = ecol[i];
        float va = ql_a * b2f(ka[(size_t)c * D + lane]);
        float vb = ql_b * b2f(kb[(size_t)c * D + lane]);
#pragma unroll
        for (int off = 1; off < 64; off <<= 1) {
          va += __shfl_xor(va, off);
          vb += __shfl_xor(vb, off);
        }
        va *= scale; vb *= scale;
        float na = fmaxf(ma, va);
        da = da * __expf(ma - na) + __expf(va - na);
        ma = na;
        float nb2 = fmaxf(mb, vb);
        db = db * __expf(mb - nb2) + __expf(vb - nb2);
        mb = nb2;
      }
      const float ia = 1.0f / da, ib = 1.0f / db;
      for (int i = s; i < e; ++i) {
        int c = ecol[i];
        float va = ql_a * b2f(ka[(size_t)c * D + lane]);
        float vb = ql_b * b2f(kb[(size_t)c * D + lane]);
#pragma unroll
        for (int off = 1; off < 64; off <<= 1) {
          va += __shfl_xor(va, off);
          vb += __shfl_xor(vb, off);
        }
        float al = __expf(va * scale - ma) * ia;
        float be = __expf(vb * scale - mb) * ib;
        acc_t = fmaf(al, b2f(vt[(size_t)c * D + lane]), acc_t);
        acc_x = fmaf(be, b2f(vx[(size_t)c * D + lane]), acc_x);
      }
    }
    out_t[nb + lane] = acc_t;
    out_x[nb + lane] = acc_x;
  }
}

// ---------------------------------------------------------------------------
extern "C" void kernel_launch(void* const* d_in, const int* in_sizes, int n_in,
                              void* d_out, int out_size, void* d_ws, size_t ws_size,
                              hipStream_t stream) {
  const float* x_src = (const float*)d_in[0];
  const float* x_tgt = (const float*)d_in[1];
  const float* t_src = (const float*)d_in[2];
  const float* t_tgt = (const float*)d_in[3];
  const void* edge_index = d_in[4];
  const float* W_x = (const float*)d_in[5];
  const float* W_t = (const float*)d_in[6];
  const float* Ka_W = (const float*)d_in[7];
  const float* Ka_b = (const float*)d_in[8];
  const float* Qa_W = (const float*)d_in[9];
  const float* Qa_b = (const float*)d_in[10];
  const float* Kb_W = (const float*)d_in[11];
  const float* Kb_b = (const float*)d_in[12];
  const float* Qb_W = (const float*)d_in[13];
  const float* Qb_b = (const float*)d_in[14];

  const int N = in_sizes[0] / D;
  const int E = in_sizes[4] / 2;
  const int nB = (N + 255) / 256;  // <= 256

  char* ws = (char*)d_ws;
  size_t ofs = 0;
  auto carve = [&](size_t bytes) {
    size_t p = ofs;
    ofs += (bytes + 255) & ~(size_t)255;
    return p;
  };
  float* qa = (float*)(ws + carve((size_t)N * D * 4));
  float* qb = (float*)(ws + carve((size_t)N * D * 4));
  ushortT* ka = (ushortT*)(ws + carve((size_t)N * D * 2));
  ushortT* kb = (ushortT*)(ws + carve((size_t)N * D * 2));
  ushortT* vt = (ushortT*)(ws + carve((size_t)N * D * 2));
  ushortT* vx = (ushortT*)(ws + carve((size_t)N * D * 2));
  int* offs = (int*)(ws + carve(((size_t)N + 1) * 4));
  int* deg = (int*)(ws + carve((size_t)N * 4));
  int* cursor = (int*)(ws + carve((size_t)N * 4));
  int* bsum = (int*)(ws + carve((size_t)nB * 4));
  int* ecol = (int*)(ws + carve((size_t)E * 4));
  int* flag = (int*)(ws + carve(4));
  (void)ws_size;

  float* out_x = (float*)d_out;
  float* out_t = out_x + (size_t)N * D;

  const int e4Blocks = ((E + 3) / 4 + 255) / 256;

  detect_idx64<<<1, 1, 0, stream>>>((const unsigned long long*)edge_index, flag, 16,
                                    (unsigned long long)N);
  hipMemsetAsync(deg, 0, (size_t)N * 4, stream);
  edge_degree<<<e4Blocks, 256, 0, stream>>>(edge_index, flag, deg, E);
  scan_block_sums<<<nB, 256, 0, stream>>>(deg, bsum, N);
  scan_exclusive_small<<<1, 256, 0, stream>>>(bsum, nB);
  scan_finalize<<<nB, 256, 0, stream>>>(deg, bsum, offs, cursor, N, E);
  scatter_edges<<<e4Blocks, 256, 0, stream>>>(edge_index, flag, cursor, ecol, E);

  const int bpj = 384;
  proj_single<<<2 * bpj, 256, 0, stream>>>(t_tgt, Qa_W, Qa_b, qa,
                                           x_tgt, Qb_W, Qb_b, qb, N, bpj);
  proj_dual<<<2 * bpj, 256, 0, stream>>>(t_src, Ka_W, Ka_b, W_t, ka, vt,
                                         x_src, Kb_W, Kb_b, W_x, kb, vx, N, bpj);

  node_attn<<<(N + 3) / 4, 256, 0, stream>>>(qa, qb, ka, kb, vt, vx, offs, ecol,
                                             out_x, out_t, N);
}

// Round 3
// 396.451 us; speedup vs baseline: 1.5877x; 1.3197x over previous
//
#include <hip/hip_runtime.h>
#include <math.h>

// ---------------------------------------------------------------------------
// CrossAttentionGNNConv: N=50000, E=800000, D=64
// CSR by destination row -> per-wave node attention.
// K/V arrays (ka,kb,vt,vx) stored bf16 (halves gather bytes); fp32 math.
// Projections: single LDS-tiled register-blocked GEMM kernel (4 jobs).
// ---------------------------------------------------------------------------

#define D 64
#define CAP 96
#define NINF -3.0e38f
typedef unsigned short ushortT;
typedef unsigned long long ull;

__device__ __forceinline__ float b2f(ushortT h) {
  return __uint_as_float(((unsigned)h) << 16);
}
__device__ __forceinline__ ushortT f2b(float f) {
  unsigned u = __float_as_uint(f);
  u += 0x7fffu + ((u >> 16) & 1u);
  return (ushortT)(u >> 16);
}

// --- edge_index dtype detection (int32 vs int64) ---------------------------
// Reads first 64 u64 words; if any >= nNodes the data must be int32.
__global__ void detect_idx64(const ull* __restrict__ ei, int* __restrict__ flag,
                             ull nNodes) {
  ull v = ei[threadIdx.x];
  unsigned long long ball = __ballot(v >= nNodes);
  if (threadIdx.x == 0) *flag = (ball == 0ull) ? 1 : 0;
}

// --- CSR build -------------------------------------------------------------
__global__ void edge_degree(const void* __restrict__ ei, const int* __restrict__ flag,
                            int* __restrict__ deg, int E) {
  int base = (blockIdx.x * blockDim.x + threadIdx.x) << 2;
  if (base >= E) return;
  const bool is64 = (*flag) != 0;
  if (base + 4 <= E) {
    int r0, r1, r2, r3;
    if (is64) {
      const long long* p = (const long long*)ei;
      r0 = (int)p[base]; r1 = (int)p[base + 1];
      r2 = (int)p[base + 2]; r3 = (int)p[base + 3];
    } else {
      const int* p = (const int*)ei;
      r0 = p[base]; r1 = p[base + 1]; r2 = p[base + 2]; r3 = p[base + 3];
    }
    atomicAdd(&deg[r0], 1); atomicAdd(&deg[r1], 1);
    atomicAdd(&deg[r2], 1); atomicAdd(&deg[r3], 1);
  } else {
    for (int j = base; j < E; ++j) {
      int r = is64 ? (int)((const long long*)ei)[j] : ((const int*)ei)[j];
      atomicAdd(&deg[r], 1);
    }
  }
}

__global__ void scan_block_sums(const int* __restrict__ deg, int* __restrict__ bsum, int N) {
  __shared__ int sdata[256];
  int i = blockIdx.x * 256 + threadIdx.x;
  sdata[threadIdx.x] = (i < N) ? deg[i] : 0;
  __syncthreads();
  for (int s = 128; s > 0; s >>= 1) {
    if (threadIdx.x < s) sdata[threadIdx.x] += sdata[threadIdx.x + s];
    __syncthreads();
  }
  if (threadIdx.x == 0) bsum[blockIdx.x] = sdata[0];
}

__global__ void scan_exclusive_small(int* __restrict__ bsum, int nB) {
  __shared__ int sdata[256];
  int t = threadIdx.x;
  int v = (t < nB) ? bsum[t] : 0;
  sdata[t] = v;
  __syncthreads();
  for (int off = 1; off < 256; off <<= 1) {
    int add = (t >= off) ? sdata[t - off] : 0;
    __syncthreads();
    sdata[t] += add;
    __syncthreads();
  }
  if (t < nB) bsum[t] = sdata[t] - v;
}

__global__ void scan_finalize(const int* __restrict__ deg, const int* __restrict__ bsum,
                              int* __restrict__ offs, int* __restrict__ cursor,
                              int N, int E) {
  __shared__ int sdata[256];
  int t = threadIdx.x;
  int i = blockIdx.x * 256 + t;
  int v = (i < N) ? deg[i] : 0;
  sdata[t] = v;
  __syncthreads();
  for (int off = 1; off < 256; off <<= 1) {
    int add = (t >= off) ? sdata[t - off] : 0;
    __syncthreads();
    sdata[t] += add;
    __syncthreads();
  }
  int excl = sdata[t] - v + bsum[blockIdx.x];
  if (i < N) { offs[i] = excl; cursor[i] = excl; }
  if (blockIdx.x == 0 && t == 0) offs[N] = E;
}

__global__ void scatter_edges(const void* __restrict__ ei, const int* __restrict__ flag,
                              int* __restrict__ cursor, int* __restrict__ ecol, int E) {
  int base = (blockIdx.x * blockDim.x + threadIdx.x) << 2;
  if (base >= E) return;
  const bool is64 = (*flag) != 0;
  int m = E - base; if (m > 4) m = 4;
  if (is64) {
    const long long* p = (const long long*)ei;
    for (int j = 0; j < m; ++j) {
      int r = (int)p[base + j];
      int c = (int)p[(long long)E + base + j];
      int pos = atomicAdd(&cursor[r], 1);
      ecol[pos] = c;
    }
  } else {
    const int* p = (const int*)ei;
    for (int j = 0; j < m; ++j) {
      int r = p[base + j];
      int c = p[E + base + j];
      int pos = atomicAdd(&cursor[r], 1);
      ecol[pos] = c;
    }
  }
}

// --- projections: one LDS-tiled register-blocked GEMM kernel ---------------
// Tile: 128 nodes x 64 outs, k split in two phases of 32.
// Thread (256/block): og = tid&15 -> outs {og+16j}, ng = tid>>4 -> nodes
// {ng+16i}. LDS rows stride 36 floats (16B-aligned; consecutive-row access
// across 16 lanes -> exactly 2-way bank aliasing = free).
// Jobs: 0: t_tgt->qa(f32,+b) 1: x_tgt->qb 2: t_src->{ka(+b),vt} bf16
//       3: x_src->{kb(+b),vx} bf16
#define XS 36

__global__ __launch_bounds__(256) void proj_all(
    const float* __restrict__ t_tgt, const float* __restrict__ x_tgt,
    const float* __restrict__ t_src, const float* __restrict__ x_src,
    const float* __restrict__ QaW, const float* __restrict__ Qab,
    const float* __restrict__ QbW, const float* __restrict__ Qbb,
    const float* __restrict__ KaW, const float* __restrict__ Kab,
    const float* __restrict__ Wt,
    const float* __restrict__ KbW, const float* __restrict__ Kbb,
    const float* __restrict__ Wx,
    float* __restrict__ qa, float* __restrict__ qb,
    ushortT* __restrict__ ka, ushortT* __restrict__ vt,
    ushortT* __restrict__ kb, ushortT* __restrict__ vx,
    int nNodes, int bpj) {
  __shared__ float xs[128 * XS];
  __shared__ float w0s[64 * XS];
  __shared__ float w1s[64 * XS];
  const int job = blockIdx.x / bpj;
  const int jb = blockIdx.x % bpj;
  const float *X, *W0, *B0, *W1 = nullptr;
  float* outF = nullptr;
  ushortT *o0 = nullptr, *o1 = nullptr;
  switch (job) {
    case 0: X = t_tgt; W0 = QaW; B0 = Qab; outF = qa; break;
    case 1: X = x_tgt; W0 = QbW; B0 = Qbb; outF = qb; break;
    case 2: X = t_src; W0 = KaW; B0 = Kab; W1 = Wt; o0 = ka; o1 = vt; break;
    default: X = x_src; W0 = KbW; B0 = Kbb; W1 = Wx; o0 = kb; o1 = vx; break;
  }
  const bool dual = (job >= 2);
  const int tid = threadIdx.x;
  const int og = tid & 15, ng = tid >> 4;
  const int base = jb * 128;

  float acc0[8][4], acc1[8][4];
#pragma unroll
  for (int i = 0; i < 8; ++i)
#pragma unroll
    for (int j = 0; j < 4; ++j) { acc0[i][j] = 0.f; acc1[i][j] = 0.f; }

  for (int ph = 0; ph < 2; ++ph) {
    if (ph) __syncthreads();
    // stage X tile (128 x 32)
#pragma unroll
    for (int r = 0; r < 4; ++r) {
      int idx = tid + 256 * r;  // 0..1023
      int nrow = idx >> 3, c4 = idx & 7;
      int gnode = base + nrow;
      float4 v = make_float4(0.f, 0.f, 0.f, 0.f);
      if (gnode < nNodes)
        v = *(const float4*)(X + (size_t)gnode * D + ph * 32 + c4 * 4);
      *(float4*)&xs[nrow * XS + c4 * 4] = v;
    }
    // stage W0 (64 x 32)
#pragma unroll
    for (int r = 0; r < 2; ++r) {
      int idx = tid + 256 * r;  // 0..511
      int wrow = idx >> 3, c4 = idx & 7;
      *(float4*)&w0s[wrow * XS + c4 * 4] =
          *(const float4*)(W0 + wrow * D + ph * 32 + c4 * 4);
    }
    if (dual) {
#pragma unroll
      for (int r = 0; r < 2; ++r) {
        int idx = tid + 256 * r;
        int wrow = idx >> 3, c4 = idx & 7;
        *(float4*)&w1s[wrow * XS + c4 * 4] =
            *(const float4*)(W1 + wrow * D + ph * 32 + c4 * 4);
      }
    }
    __syncthreads();

    if (!dual) {
#pragma unroll
      for (int k4 = 0; k4 < 8; ++k4) {
        float4 wv0[4];
#pragma unroll
        for (int j = 0; j < 4; ++j)
          wv0[j] = *(const float4*)&w0s[(og + 16 * j) * XS + k4 * 4];
#pragma unroll
        for (int i = 0; i < 8; ++i) {
          float4 xv = *(const float4*)&xs[(ng + 16 * i) * XS + k4 * 4];
#pragma unroll
          for (int j = 0; j < 4; ++j) {
            acc0[i][j] = fmaf(xv.x, wv0[j].x, acc0[i][j]);
            acc0[i][j] = fmaf(xv.y, wv0[j].y, acc0[i][j]);
            acc0[i][j] = fmaf(xv.z, wv0[j].z, acc0[i][j]);
            acc0[i][j] = fmaf(xv.w, wv0[j].w, acc0[i][j]);
          }
        }
      }
    } else {
#pragma unroll
      for (int k4 = 0; k4 < 8; ++k4) {
        float4 wv0[4], wv1[4];
#pragma unroll
        for (int j = 0; j < 4; ++j) {
          wv0[j] = *(const float4*)&w0s[(og + 16 * j) * XS + k4 * 4];
          wv1[j] = *(const float4*)&w1s[(og + 16 * j) * XS + k4 * 4];
        }
#pragma unroll
        for (int i = 0; i < 8; ++i) {
          float4 xv = *(const float4*)&xs[(ng + 16 * i) * XS + k4 * 4];
#pragma unroll
          for (int j = 0; j < 4; ++j) {
            acc0[i][j] = fmaf(xv.x, wv0[j].x, acc0[i][j]);
            acc0[i][j] = fmaf(xv.y, wv0[j].y, acc0[i][j]);
            acc0[i][j] = fmaf(xv.z, wv0[j].z, acc0[i][j]);
            acc0[i][j] = fmaf(xv.w, wv0[j].w, acc0[i][j]);
            acc1[i][j] = fmaf(xv.x, wv1[j].x, acc1[i][j]);
            acc1[i][j] = fmaf(xv.y, wv1[j].y, acc1[i][j]);
            acc1[i][j] = fmaf(xv.z, wv1[j].z, acc1[i][j]);
            acc1[i][j] = fmaf(xv.w, wv1[j].w, acc1[i][j]);
          }
        }
      }
    }
  }

  // epilogue
  float bj[4];
#pragma unroll
  for (int j = 0; j < 4; ++j) bj[j] = B0[og + 16 * j];
  if (!dual) {
#pragma unroll
    for (int i = 0; i < 8; ++i) {
      int node = base + ng + 16 * i;
      if (node < nNodes) {
#pragma unroll
        for (int j = 0; j < 4; ++j)
          outF[(size_t)node * D + og + 16 * j] = acc0[i][j] + bj[j];
      }
    }
  } else {
#pragma unroll
    for (int i = 0; i < 8; ++i) {
      int node = base + ng + 16 * i;
      if (node < nNodes) {
#pragma unroll
        for (int j = 0; j < 4; ++j) {
          o0[(size_t)node * D + og + 16 * j] = f2b(acc0[i][j] + bj[j]);
          o1[(size_t)node * D + og + 16 * j] = f2b(acc1[i][j]);
        }
      }
    }
  }
}

// --- per-node attention + aggregation, one wave per destination node -------
__global__ __launch_bounds__(256) void node_attn(
    const float* __restrict__ qa, const float* __restrict__ qb,
    const ushortT* __restrict__ ka, const ushortT* __restrict__ kb,
    const ushortT* __restrict__ vt, const ushortT* __restrict__ vx,
    const int* __restrict__ offs, const int* __restrict__ ecol,
    float* __restrict__ out_x, float* __restrict__ out_t, int nNodes) {
  __shared__ float s_wa[4][CAP];
  __shared__ float s_wb[4][CAP];
  const int lane = threadIdx.x & 63;
  const int wid = threadIdx.x >> 6;
  const int sub = lane >> 4;
  const int sl = lane & 15;
  const int gw = (blockIdx.x * blockDim.x + threadIdx.x) >> 6;
  const int nw = (gridDim.x * blockDim.x) >> 6;
  const float scale = 0.125f;

  for (int n = gw; n < nNodes; n += nw) {
    const int s = offs[n], e = offs[n + 1], deg = e - s;
    const size_t nb = (size_t)n * D;
    if (deg == 0) {
      out_x[nb + lane] = 0.f;
      out_t[nb + lane] = 0.f;
      continue;
    }
    float acc_t = 0.f, acc_x = 0.f;
    if (deg <= CAP) {
      const float4 q4a = *(const float4*)(qa + nb + sl * 4);
      const float4 q4b = *(const float4*)(qb + nb + sl * 4);
      for (int i = 0; i < deg; i += 4) {
        const int idx = i + sub;
        const int c = ecol[s + (idx < deg ? idx : 0)];
        const size_t cb = (size_t)c * D + sl * 4;
        ushort4 ha = *(const ushort4*)(ka + cb);
        ushort4 hb = *(const ushort4*)(kb + cb);
        float va = q4a.x * b2f(ha.x);
        va = fmaf(q4a.y, b2f(ha.y), va);
        va = fmaf(q4a.z, b2f(ha.z), va);
        va = fmaf(q4a.w, b2f(ha.w), va);
        float vb = q4b.x * b2f(hb.x);
        vb = fmaf(q4b.y, b2f(hb.y), vb);
        vb = fmaf(q4b.z, b2f(hb.z), vb);
        vb = fmaf(q4b.w, b2f(hb.w), vb);
#pragma unroll
        for (int off = 1; off < 16; off <<= 1) {
          va += __shfl_xor(va, off);
          vb += __shfl_xor(vb, off);
        }
        if (sl == 0 && idx < deg) {
          s_wa[wid][idx] = va * scale;
          s_wb[wid][idx] = vb * scale;
        }
      }
      float sa0 = (lane < deg) ? s_wa[wid][lane] : NINF;
      float sb0 = (lane < deg) ? s_wb[wid][lane] : NINF;
      float sa1 = (lane + 64 < deg) ? s_wa[wid][lane + 64] : NINF;
      float sb1 = (lane + 64 < deg) ? s_wb[wid][lane + 64] : NINF;
      float ma = fmaxf(sa0, sa1), mb = fmaxf(sb0, sb1);
#pragma unroll
      for (int off = 1; off < 64; off <<= 1) {
        ma = fmaxf(ma, __shfl_xor(ma, off));
        mb = fmaxf(mb, __shfl_xor(mb, off));
      }
      float ea0 = __expf(sa0 - ma), ea1 = __expf(sa1 - ma);
      float eb0 = __expf(sb0 - mb), eb1 = __expf(sb1 - mb);
      float da = ea0 + ea1, db = eb0 + eb1;
#pragma unroll
      for (int off = 1; off < 64; off <<= 1) {
        da += __shfl_xor(da, off);
        db += __shfl_xor(db, off);
      }
      const float ia = 1.0f / da, ib = 1.0f / db;
      if (lane < deg) { s_wa[wid][lane] = ea0 * ia; s_wb[wid][lane] = eb0 * ib; }
      if (lane + 64 < deg) { s_wa[wid][lane + 64] = ea1 * ia; s_wb[wid][lane + 64] = eb1 * ib; }
      int i = 0;
      for (; i + 2 <= deg; i += 2) {
        int c0 = ecol[s + i], c1 = ecol[s + i + 1];
        float wa0 = s_wa[wid][i], wa1 = s_wa[wid][i + 1];
        float wb0 = s_wb[wid][i], wb1 = s_wb[wid][i + 1];
        float t0 = b2f(vt[(size_t)c0 * D + lane]);
        float x0 = b2f(vx[(size_t)c0 * D + lane]);
        float t1 = b2f(vt[(size_t)c1 * D + lane]);
        float x1 = b2f(vx[(size_t)c1 * D + lane]);
        acc_t = fmaf(wa0, t0, acc_t);
        acc_t = fmaf(wa1, t1, acc_t);
        acc_x = fmaf(wb0, x0, acc_x);
        acc_x = fmaf(wb1, x1, acc_x);
      }
      if (i < deg) {
        int c0 = ecol[s + i];
        acc_t = fmaf(s_wa[wid][i], b2f(vt[(size_t)c0 * D + lane]), acc_t);
        acc_x = fmaf(s_wb[wid][i], b2f(vx[(size_t)c0 * D + lane]), acc_x);
      }
    } else {
      const float ql_a = qa[nb + lane];
      const float ql_b = qb[nb + lane];
      float ma = NINF, mb = NINF, da = 0.f, db = 0.f;
      for (int i = s; i < e; ++i) {
        int c = ecol[i];
        float va = ql_a * b2f(ka[(size_t)c * D + lane]);
        float vb = ql_b * b2f(kb[(size_t)c * D + lane]);
#pragma unroll
        for (int off = 1; off < 64; off <<= 1) {
          va += __shfl_xor(va, off);
          vb += __shfl_xor(vb, off);
        }
        va *= scale; vb *= scale;
        float na = fmaxf(ma, va);
        da = da * __expf(ma - na) + __expf(va - na);
        ma = na;
        float nb2 = fmaxf(mb, vb);
        db = db * __expf(mb - nb2) + __expf(vb - nb2);
        mb = nb2;
      }
      const float ia = 1.0f / da, ib = 1.0f / db;
      for (int i = s; i < e; ++i) {
        int c = ecol[i];
        float va = ql_a * b2f(ka[(size_t)c * D + lane]);
        float vb = ql_b * b2f(kb[(size_t)c * D + lane]);
#pragma unroll
        for (int off = 1; off < 64; off <<= 1) {
          va += __shfl_xor(va, off);
          vb += __shfl_xor(vb, off);
        }
        float al = __expf(va * scale - ma) * ia;
        float be = __expf(vb * scale - mb) * ib;
        acc_t = fmaf(al, b2f(vt[(size_t)c * D + lane]), acc_t);
        acc_x = fmaf(be, b2f(vx[(size_t)c * D + lane]), acc_x);
      }
    }
    out_t[nb + lane] = acc_t;
    out_x[nb + lane] = acc_x;
  }
}

// ---------------------------------------------------------------------------
extern "C" void kernel_launch(void* const* d_in, const int* in_sizes, int n_in,
                              void* d_out, int out_size, void* d_ws, size_t ws_size,
                              hipStream_t stream) {
  const float* x_src = (const float*)d_in[0];
  const float* x_tgt = (const float*)d_in[1];
  const float* t_src = (const float*)d_in[2];
  const float* t_tgt = (const float*)d_in[3];
  const void* edge_index = d_in[4];
  const float* W_x = (const float*)d_in[5];
  const float* W_t = (const float*)d_in[6];
  const float* Ka_W = (const float*)d_in[7];
  const float* Ka_b = (const float*)d_in[8];
  const float* Qa_W = (const float*)d_in[9];
  const float* Qa_b = (const float*)d_in[10];
  const float* Kb_W = (const float*)d_in[11];
  const float* Kb_b = (const float*)d_in[12];
  const float* Qb_W = (const float*)d_in[13];
  const float* Qb_b = (const float*)d_in[14];

  const int N = in_sizes[0] / D;
  const int E = in_sizes[4] / 2;
  const int nB = (N + 255) / 256;  // <= 256

  char* ws = (char*)d_ws;
  size_t ofs = 0;
  auto carve = [&](size_t bytes) {
    size_t p = ofs;
    ofs += (bytes + 255) & ~(size_t)255;
    return p;
  };
  float* qa = (float*)(ws + carve((size_t)N * D * 4));
  float* qb = (float*)(ws + carve((size_t)N * D * 4));
  ushortT* ka = (ushortT*)(ws + carve((size_t)N * D * 2));
  ushortT* kb = (ushortT*)(ws + carve((size_t)N * D * 2));
  ushortT* vt = (ushortT*)(ws + carve((size_t)N * D * 2));
  ushortT* vx = (ushortT*)(ws + carve((size_t)N * D * 2));
  int* offs = (int*)(ws + carve(((size_t)N + 1) * 4));
  int* deg = (int*)(ws + carve((size_t)N * 4));
  int* cursor = (int*)(ws + carve((size_t)N * 4));
  int* bsum = (int*)(ws + carve((size_t)nB * 4));
  int* ecol = (int*)(ws + carve((size_t)E * 4));
  int* flag = (int*)(ws + carve(4));
  (void)ws_size;

  float* out_x = (float*)d_out;
  float* out_t = out_x + (size_t)N * D;

  const int e4Blocks = ((E + 3) / 4 + 255) / 256;

  detect_idx64<<<1, 64, 0, stream>>>((const ull*)edge_index, flag,
                                     (unsigned long long)N);
  hipMemsetAsync(deg, 0, (size_t)N * 4, stream);
  edge_degree<<<e4Blocks, 256, 0, stream>>>(edge_index, flag, deg, E);
  scan_block_sums<<<nB, 256, 0, stream>>>(deg, bsum, N);
  scan_exclusive_small<<<1, 256, 0, stream>>>(bsum, nB);
  scan_finalize<<<nB, 256, 0, stream>>>(deg, bsum, offs, cursor, N, E);
  scatter_edges<<<e4Blocks, 256, 0, stream>>>(edge_index, flag, cursor, ecol, E);

  const int bpj = (N + 127) / 128;
  proj_all<<<4 * bpj, 256, 0, stream>>>(t_tgt, x_tgt, t_src, x_src,
                                        Qa_W, Qa_b, Qb_W, Qb_b,
                                        Ka_W, Ka_b, W_t,
                                        Kb_W, Kb_b, W_x,
                                        qa, qb, ka, vt, kb, vx, N, bpj);

  node_attn<<<(N + 3) / 4, 256, 0, stream>>>(qa, qb, ka, kb, vt, vx, offs, ecol,
                                             out_x, out_t, N);
}

// Round 4
// 359.120 us; speedup vs baseline: 1.7528x; 1.1040x over previous
//
#include <hip/hip_runtime.h>
#include <math.h>

// ---------------------------------------------------------------------------
// CrossAttentionGNNConv: N=50000, E=800000, D=64
// CSR by destination row -> per-wave node attention.
// Interleaved per-node layouts:
//   qab[n][128] fp32  = [q_alpha | q_beta]
//   kab[n][128] bf16  = [k_alpha | k_beta]
//   vtx[n][128] bf16  = [v_t     | v_x   ]
// ---------------------------------------------------------------------------

#define D 64
#define CAP 96
#define NINF -3.0e38f
typedef unsigned short ushortT;
typedef unsigned long long ull;

__device__ __forceinline__ float b2f(ushortT h) {
  return __uint_as_float(((unsigned)h) << 16);
}
__device__ __forceinline__ float b2f_lo(unsigned u) {
  return __uint_as_float(u << 16);
}
__device__ __forceinline__ float b2f_hi(unsigned u) {
  return __uint_as_float(u & 0xffff0000u);
}
__device__ __forceinline__ ushortT f2b(float f) {
  unsigned u = __float_as_uint(f);
  u += 0x7fffu + ((u >> 16) & 1u);
  return (ushortT)(u >> 16);
}

// inline edge dtype detection: first 64 u64 words; any >= nNodes -> int32
__device__ __forceinline__ bool wave_is64(const ull* __restrict__ ei, ull nNodes) {
  ull v = ei[threadIdx.x & 63];
  return __ballot(v >= nNodes) == 0ull;
}

// --- CSR build -------------------------------------------------------------
__global__ void edge_degree(const void* __restrict__ ei, int* __restrict__ deg,
                            int E, ull nNodes) {
  const bool is64 = wave_is64((const ull*)ei, nNodes);
  int base = (blockIdx.x * blockDim.x + threadIdx.x) << 2;
  if (base >= E) return;
  if (base + 4 <= E) {
    int r0, r1, r2, r3;
    if (is64) {
      const long long* p = (const long long*)ei;
      r0 = (int)p[base]; r1 = (int)p[base + 1];
      r2 = (int)p[base + 2]; r3 = (int)p[base + 3];
    } else {
      const int* p = (const int*)ei;
      r0 = p[base]; r1 = p[base + 1]; r2 = p[base + 2]; r3 = p[base + 3];
    }
    atomicAdd(&deg[r0], 1); atomicAdd(&deg[r1], 1);
    atomicAdd(&deg[r2], 1); atomicAdd(&deg[r3], 1);
  } else {
    for (int j = base; j < E; ++j) {
      int r = is64 ? (int)((const long long*)ei)[j] : ((const int*)ei)[j];
      atomicAdd(&deg[r], 1);
    }
  }
}

__global__ void scan_block_sums(const int* __restrict__ deg, int* __restrict__ bsum, int N) {
  __shared__ int sdata[256];
  int i = blockIdx.x * 256 + threadIdx.x;
  sdata[threadIdx.x] = (i < N) ? deg[i] : 0;
  __syncthreads();
  for (int s = 128; s > 0; s >>= 1) {
    if (threadIdx.x < s) sdata[threadIdx.x] += sdata[threadIdx.x + s];
    __syncthreads();
  }
  if (threadIdx.x == 0) bsum[blockIdx.x] = sdata[0];
}

__global__ void scan_exclusive_small(int* __restrict__ bsum, int nB) {
  __shared__ int sdata[256];
  int t = threadIdx.x;
  int v = (t < nB) ? bsum[t] : 0;
  sdata[t] = v;
  __syncthreads();
  for (int off = 1; off < 256; off <<= 1) {
    int add = (t >= off) ? sdata[t - off] : 0;
    __syncthreads();
    sdata[t] += add;
    __syncthreads();
  }
  if (t < nB) bsum[t] = sdata[t] - v;
}

__global__ void scan_finalize(const int* __restrict__ deg, const int* __restrict__ bsum,
                              int* __restrict__ offs, int* __restrict__ cursor,
                              int N, int E) {
  __shared__ int sdata[256];
  int t = threadIdx.x;
  int i = blockIdx.x * 256 + t;
  int v = (i < N) ? deg[i] : 0;
  sdata[t] = v;
  __syncthreads();
  for (int off = 1; off < 256; off <<= 1) {
    int add = (t >= off) ? sdata[t - off] : 0;
    __syncthreads();
    sdata[t] += add;
    __syncthreads();
  }
  int excl = sdata[t] - v + bsum[blockIdx.x];
  if (i < N) { offs[i] = excl; cursor[i] = excl; }
  if (blockIdx.x == 0 && t == 0) offs[N] = E;
}

__global__ void scatter_edges(const void* __restrict__ ei, int* __restrict__ cursor,
                              int* __restrict__ ecol, int E, ull nNodes) {
  const bool is64 = wave_is64((const ull*)ei, nNodes);
  int base = (blockIdx.x * blockDim.x + threadIdx.x) << 2;
  if (base >= E) return;
  int m = E - base; if (m > 4) m = 4;
  if (is64) {
    const long long* p = (const long long*)ei;
    for (int j = 0; j < m; ++j) {
      int r = (int)p[base + j];
      int c = (int)p[(long long)E + base + j];
      int pos = atomicAdd(&cursor[r], 1);
      ecol[pos] = c;
    }
  } else {
    const int* p = (const int*)ei;
    for (int j = 0; j < m; ++j) {
      int r = p[base + j];
      int c = p[E + base + j];
      int pos = atomicAdd(&cursor[r], 1);
      ecol[pos] = c;
    }
  }
}

// --- projections: one LDS-tiled register-blocked GEMM kernel ---------------
// Tile: 128 nodes x 64 outs, k split in two phases of 32. LDS rows stride 36.
// Jobs write into interleaved halves (row stride 128):
//  0: t_tgt @ QaW.T + b -> qab[:,0:64)   1: x_tgt @ QbW.T + b -> qab[:,64:128)
//  2: t_src -> kab[:,0:64)(+b), vtx[:,0:64)
//  3: x_src -> kab[:,64:128)(+b), vtx[:,64:128)
#define XS 36

__global__ __launch_bounds__(256) void proj_all(
    const float* __restrict__ t_tgt, const float* __restrict__ x_tgt,
    const float* __restrict__ t_src, const float* __restrict__ x_src,
    const float* __restrict__ QaW, const float* __restrict__ Qab_,
    const float* __restrict__ QbW, const float* __restrict__ Qbb,
    const float* __restrict__ KaW, const float* __restrict__ Kab_,
    const float* __restrict__ Wt,
    const float* __restrict__ KbW, const float* __restrict__ Kbb,
    const float* __restrict__ Wx,
    float* __restrict__ qab, ushortT* __restrict__ kab, ushortT* __restrict__ vtx,
    int nNodes, int bpj) {
  __shared__ float xs[128 * XS];
  __shared__ float w0s[64 * XS];
  __shared__ float w1s[64 * XS];
  const int job = blockIdx.x / bpj;
  const int jb = blockIdx.x % bpj;
  const float *X, *W0, *B0, *W1 = nullptr;
  switch (job) {
    case 0: X = t_tgt; W0 = QaW; B0 = Qab_; break;
    case 1: X = x_tgt; W0 = QbW; B0 = Qbb; break;
    case 2: X = t_src; W0 = KaW; B0 = Kab_; W1 = Wt; break;
    default: X = x_src; W0 = KbW; B0 = Kbb; W1 = Wx; break;
  }
  const bool dual = (job >= 2);
  const int half = (job & 1) ? 64 : 0;  // jobs 1,3 write the upper half
  const int tid = threadIdx.x;
  const int og = tid & 15, ng = tid >> 4;
  const int base = jb * 128;

  float acc0[8][4], acc1[8][4];
#pragma unroll
  for (int i = 0; i < 8; ++i)
#pragma unroll
    for (int j = 0; j < 4; ++j) { acc0[i][j] = 0.f; acc1[i][j] = 0.f; }

  for (int ph = 0; ph < 2; ++ph) {
    if (ph) __syncthreads();
#pragma unroll
    for (int r = 0; r < 4; ++r) {
      int idx = tid + 256 * r;
      int nrow = idx >> 3, c4 = idx & 7;
      int gnode = base + nrow;
      float4 v = make_float4(0.f, 0.f, 0.f, 0.f);
      if (gnode < nNodes)
        v = *(const float4*)(X + (size_t)gnode * D + ph * 32 + c4 * 4);
      *(float4*)&xs[nrow * XS + c4 * 4] = v;
    }
#pragma unroll
    for (int r = 0; r < 2; ++r) {
      int idx = tid + 256 * r;
      int wrow = idx >> 3, c4 = idx & 7;
      *(float4*)&w0s[wrow * XS + c4 * 4] =
          *(const float4*)(W0 + wrow * D + ph * 32 + c4 * 4);
    }
    if (dual) {
#pragma unroll
      for (int r = 0; r < 2; ++r) {
        int idx = tid + 256 * r;
        int wrow = idx >> 3, c4 = idx & 7;
        *(float4*)&w1s[wrow * XS + c4 * 4] =
            *(const float4*)(W1 + wrow * D + ph * 32 + c4 * 4);
      }
    }
    __syncthreads();

    if (!dual) {
#pragma unroll
      for (int k4 = 0; k4 < 8; ++k4) {
        float4 wv0[4];
#pragma unroll
        for (int j = 0; j < 4; ++j)
          wv0[j] = *(const float4*)&w0s[(og + 16 * j) * XS + k4 * 4];
#pragma unroll
        for (int i = 0; i < 8; ++i) {
          float4 xv = *(const float4*)&xs[(ng + 16 * i) * XS + k4 * 4];
#pragma unroll
          for (int j = 0; j < 4; ++j) {
            acc0[i][j] = fmaf(xv.x, wv0[j].x, acc0[i][j]);
            acc0[i][j] = fmaf(xv.y, wv0[j].y, acc0[i][j]);
            acc0[i][j] = fmaf(xv.z, wv0[j].z, acc0[i][j]);
            acc0[i][j] = fmaf(xv.w, wv0[j].w, acc0[i][j]);
          }
        }
      }
    } else {
#pragma unroll
      for (int k4 = 0; k4 < 8; ++k4) {
        float4 wv0[4], wv1[4];
#pragma unroll
        for (int j = 0; j < 4; ++j) {
          wv0[j] = *(const float4*)&w0s[(og + 16 * j) * XS + k4 * 4];
          wv1[j] = *(const float4*)&w1s[(og + 16 * j) * XS + k4 * 4];
        }
#pragma unroll
        for (int i = 0; i < 8; ++i) {
          float4 xv = *(const float4*)&xs[(ng + 16 * i) * XS + k4 * 4];
#pragma unroll
          for (int j = 0; j < 4; ++j) {
            acc0[i][j] = fmaf(xv.x, wv0[j].x, acc0[i][j]);
            acc0[i][j] = fmaf(xv.y, wv0[j].y, acc0[i][j]);
            acc0[i][j] = fmaf(xv.z, wv0[j].z, acc0[i][j]);
            acc0[i][j] = fmaf(xv.w, wv0[j].w, acc0[i][j]);
            acc1[i][j] = fmaf(xv.x, wv1[j].x, acc1[i][j]);
            acc1[i][j] = fmaf(xv.y, wv1[j].y, acc1[i][j]);
            acc1[i][j] = fmaf(xv.z, wv1[j].z, acc1[i][j]);
            acc1[i][j] = fmaf(xv.w, wv1[j].w, acc1[i][j]);
          }
        }
      }
    }
  }

  float bj[4];
#pragma unroll
  for (int j = 0; j < 4; ++j) bj[j] = B0[og + 16 * j];
  if (!dual) {
#pragma unroll
    for (int i = 0; i < 8; ++i) {
      int node = base + ng + 16 * i;
      if (node < nNodes) {
        float* dst = qab + (size_t)node * 128 + half;
#pragma unroll
        for (int j = 0; j < 4; ++j) dst[og + 16 * j] = acc0[i][j] + bj[j];
      }
    }
  } else {
#pragma unroll
    for (int i = 0; i < 8; ++i) {
      int node = base + ng + 16 * i;
      if (node < nNodes) {
        ushortT* dk = kab + (size_t)node * 128 + half;
        ushortT* dv = vtx + (size_t)node * 128 + half;
#pragma unroll
        for (int j = 0; j < 4; ++j) {
          dk[og + 16 * j] = f2b(acc0[i][j] + bj[j]);
          dv[og + 16 * j] = f2b(acc1[i][j]);
        }
      }
    }
  }
}

// --- per-node attention + aggregation, one wave per destination node -------
__global__ __launch_bounds__(256) void node_attn(
    const float* __restrict__ qab, const ushortT* __restrict__ kab,
    const ushortT* __restrict__ vtx,
    const int* __restrict__ offs, const int* __restrict__ ecol,
    float* __restrict__ out_x, float* __restrict__ out_t, int nNodes) {
  __shared__ float s_wa[4][CAP];
  __shared__ float s_wb[4][CAP];
  __shared__ int s_c[4][CAP];
  const int lane = threadIdx.x & 63;
  const int wid = threadIdx.x >> 6;
  const int sub = lane >> 4;   // edge within chunk of 4
  const int sl = lane & 15;    // sublane: 0-7 -> alpha dot, 8-15 -> beta dot
  const int gw = (blockIdx.x * blockDim.x + threadIdx.x) >> 6;
  const int nw = (gridDim.x * blockDim.x) >> 6;
  const float scale = 0.125f;

  for (int n = gw; n < nNodes; n += nw) {
    const int s = offs[n], e = offs[n + 1], deg = e - s;
    const size_t nb = (size_t)n * D;
    if (deg == 0) {
      out_x[nb + lane] = 0.f;
      out_t[nb + lane] = 0.f;
      continue;
    }
    float acc_t = 0.f, acc_x = 0.f;
    if (deg <= CAP) {
      // per-lane q slice: elements sl*8 .. sl*8+7 of [q_a|q_b]
      const float4 q0 = *(const float4*)(qab + (size_t)n * 128 + sl * 8);
      const float4 q1 = *(const float4*)(qab + (size_t)n * 128 + sl * 8 + 4);
      // Phase A: scores, 4 edges per pass (16 lanes each, both dots at once)
      for (int i = 0; i < deg; i += 4) {
        const int idx = i + sub;
        const bool act = idx < deg;
        const int c = ecol[s + (act ? idx : 0)];
        const uint4 u = *(const uint4*)(kab + (size_t)c * 128 + sl * 8);
        float v = q0.x * b2f_lo(u.x);
        v = fmaf(q0.y, b2f_hi(u.x), v);
        v = fmaf(q0.z, b2f_lo(u.y), v);
        v = fmaf(q0.w, b2f_hi(u.y), v);
        v = fmaf(q1.x, b2f_lo(u.z), v);
        v = fmaf(q1.y, b2f_hi(u.z), v);
        v = fmaf(q1.z, b2f_lo(u.w), v);
        v = fmaf(q1.w, b2f_hi(u.w), v);
#pragma unroll
        for (int off = 1; off < 8; off <<= 1) v += __shfl_xor(v, off);
        if (act) {
          if (sl == 0) { s_wa[wid][idx] = v * scale; s_c[wid][idx] = c; }
          if (sl == 8) s_wb[wid][idx] = v * scale;
        }
      }
      // Phase B: parallel softmax
      float sa = (lane < deg) ? s_wa[wid][lane] : NINF;
      float sb = (lane < deg) ? s_wb[wid][lane] : NINF;
      float ma, mb, da, db;
      if (deg <= 64) {
        ma = sa; mb = sb;
#pragma unroll
        for (int off = 1; off < 64; off <<= 1) {
          ma = fmaxf(ma, __shfl_xor(ma, off));
          mb = fmaxf(mb, __shfl_xor(mb, off));
        }
        float ea = __expf(sa - ma), eb = __expf(sb - mb);
        da = ea; db = eb;
#pragma unroll
        for (int off = 1; off < 64; off <<= 1) {
          da += __shfl_xor(da, off);
          db += __shfl_xor(db, off);
        }
        const float ia = 1.0f / da, ib = 1.0f / db;
        if (lane < deg) { s_wa[wid][lane] = ea * ia; s_wb[wid][lane] = eb * ib; }
      } else {
        float sa1 = (lane + 64 < deg) ? s_wa[wid][lane + 64] : NINF;
        float sb1 = (lane + 64 < deg) ? s_wb[wid][lane + 64] : NINF;
        ma = fmaxf(sa, sa1); mb = fmaxf(sb, sb1);
#pragma unroll
        for (int off = 1; off < 64; off <<= 1) {
          ma = fmaxf(ma, __shfl_xor(ma, off));
          mb = fmaxf(mb, __shfl_xor(mb, off));
        }
        float ea0 = __expf(sa - ma), ea1 = __expf(sa1 - ma);
        float eb0 = __expf(sb - mb), eb1 = __expf(sb1 - mb);
        da = ea0 + ea1; db = eb0 + eb1;
#pragma unroll
        for (int off = 1; off < 64; off <<= 1) {
          da += __shfl_xor(da, off);
          db += __shfl_xor(db, off);
        }
        const float ia = 1.0f / da, ib = 1.0f / db;
        if (lane < deg) { s_wa[wid][lane] = ea0 * ia; s_wb[wid][lane] = eb0 * ib; }
        if (lane + 64 < deg) { s_wa[wid][lane + 64] = ea1 * ia; s_wb[wid][lane + 64] = eb1 * ib; }
      }
      // Phase C: aggregation; one base address per edge, +128B for v_x half
      int i = 0;
      for (; i + 2 <= deg; i += 2) {
        const int c0 = s_c[wid][i], c1 = s_c[wid][i + 1];
        const ushortT* b0 = vtx + (size_t)c0 * 128;
        const ushortT* b1 = vtx + (size_t)c1 * 128;
        float t0 = b2f(b0[lane]), x0 = b2f(b0[lane + 64]);
        float t1 = b2f(b1[lane]), x1 = b2f(b1[lane + 64]);
        float wa0 = s_wa[wid][i], wa1 = s_wa[wid][i + 1];
        float wb0 = s_wb[wid][i], wb1 = s_wb[wid][i + 1];
        acc_t = fmaf(wa0, t0, acc_t);
        acc_t = fmaf(wa1, t1, acc_t);
        acc_x = fmaf(wb0, x0, acc_x);
        acc_x = fmaf(wb1, x1, acc_x);
      }
      if (i < deg) {
        const int c0 = s_c[wid][i];
        const ushortT* b0 = vtx + (size_t)c0 * 128;
        acc_t = fmaf(s_wa[wid][i], b2f(b0[lane]), acc_t);
        acc_x = fmaf(s_wb[wid][i], b2f(b0[lane + 64]), acc_x);
      }
    } else {
      // rare fallback: serial full-wave online softmax + recompute
      const float qla = qab[(size_t)n * 128 + lane];
      const float qlb = qab[(size_t)n * 128 + 64 + lane];
      float ma = NINF, mb = NINF, da = 0.f, db = 0.f;
      for (int i = s; i < e; ++i) {
        int c = ecol[i];
        float va = qla * b2f(kab[(size_t)c * 128 + lane]);
        float vb = qlb * b2f(kab[(size_t)c * 128 + 64 + lane]);
#pragma unroll
        for (int off = 1; off < 64; off <<= 1) {
          va += __shfl_xor(va, off);
          vb += __shfl_xor(vb, off);
        }
        va *= scale; vb *= scale;
        float na = fmaxf(ma, va);
        da = da * __expf(ma - na) + __expf(va - na);
        ma = na;
        float nb2 = fmaxf(mb, vb);
        db = db * __expf(mb - nb2) + __expf(vb - nb2);
        mb = nb2;
      }
      const float ia = 1.0f / da, ib = 1.0f / db;
      for (int i = s; i < e; ++i) {
        int c = ecol[i];
        float va = qla * b2f(kab[(size_t)c * 128 + lane]);
        float vb = qlb * b2f(kab[(size_t)c * 128 + 64 + lane]);
#pragma unroll
        for (int off = 1; off < 64; off <<= 1) {
          va += __shfl_xor(va, off);
          vb += __shfl_xor(vb, off);
        }
        float al = __expf(va * scale - ma) * ia;
        float be = __expf(vb * scale - mb) * ib;
        const ushortT* b0 = vtx + (size_t)c * 128;
        acc_t = fmaf(al, b2f(b0[lane]), acc_t);
        acc_x = fmaf(be, b2f(b0[lane + 64]), acc_x);
      }
    }
    out_t[nb + lane] = acc_t;
    out_x[nb + lane] = acc_x;
  }
}

// ---------------------------------------------------------------------------
extern "C" void kernel_launch(void* const* d_in, const int* in_sizes, int n_in,
                              void* d_out, int out_size, void* d_ws, size_t ws_size,
                              hipStream_t stream) {
  const float* x_src = (const float*)d_in[0];
  const float* x_tgt = (const float*)d_in[1];
  const float* t_src = (const float*)d_in[2];
  const float* t_tgt = (const float*)d_in[3];
  const void* edge_index = d_in[4];
  const float* W_x = (const float*)d_in[5];
  const float* W_t = (const float*)d_in[6];
  const float* Ka_W = (const float*)d_in[7];
  const float* Ka_b = (const float*)d_in[8];
  const float* Qa_W = (const float*)d_in[9];
  const float* Qa_b = (const float*)d_in[10];
  const float* Kb_W = (const float*)d_in[11];
  const float* Kb_b = (const float*)d_in[12];
  const float* Qb_W = (const float*)d_in[13];
  const float* Qb_b = (const float*)d_in[14];

  const int N = in_sizes[0] / D;
  const int E = in_sizes[4] / 2;
  const int nB = (N + 255) / 256;  // <= 256

  char* ws = (char*)d_ws;
  size_t ofs = 0;
  auto carve = [&](size_t bytes) {
    size_t p = ofs;
    ofs += (bytes + 255) & ~(size_t)255;
    return p;
  };
  float* qab = (float*)(ws + carve((size_t)N * 128 * 4));
  ushortT* kab = (ushortT*)(ws + carve((size_t)N * 128 * 2));
  ushortT* vtx = (ushortT*)(ws + carve((size_t)N * 128 * 2));
  int* offs = (int*)(ws + carve(((size_t)N + 1) * 4));
  int* deg = (int*)(ws + carve((size_t)N * 4));
  int* cursor = (int*)(ws + carve((size_t)N * 4));
  int* bsum = (int*)(ws + carve((size_t)nB * 4));
  int* ecol = (int*)(ws + carve((size_t)E * 4));
  (void)ws_size;

  float* out_x = (float*)d_out;
  float* out_t = out_x + (size_t)N * D;

  const int e4Blocks = ((E + 3) / 4 + 255) / 256;

  hipMemsetAsync(deg, 0, (size_t)N * 4, stream);
  edge_degree<<<e4Blocks, 256, 0, stream>>>(edge_index, deg, E, (ull)N);
  scan_block_sums<<<nB, 256, 0, stream>>>(deg, bsum, N);
  scan_exclusive_small<<<1, 256, 0, stream>>>(bsum, nB);
  scan_finalize<<<nB, 256, 0, stream>>>(deg, bsum, offs, cursor, N, E);
  scatter_edges<<<e4Blocks, 256, 0, stream>>>(edge_index, cursor, ecol, E, (ull)N);

  const int bpj = (N + 127) / 128;
  proj_all<<<4 * bpj, 256, 0, stream>>>(t_tgt, x_tgt, t_src, x_src,
                                        Qa_W, Qa_b, Qb_W, Qb_b,
                                        Ka_W, Ka_b, W_t,
                                        Kb_W, Kb_b, W_x,
                                        qab, kab, vtx, N, bpj);

  node_attn<<<(N + 3) / 4, 256, 0, stream>>>(qab, kab, vtx, offs, ecol,
                                             out_x, out_t, N);
}

// Round 5
// 267.099 us; speedup vs baseline: 2.3567x; 1.3445x over previous
//
#include <hip/hip_runtime.h>
#include <math.h>

// ---------------------------------------------------------------------------
// CrossAttentionGNNConv: N=50000, E=800000, D=64
// CSR by destination row (rank-trick, atomic-free scatter) ->
// MFMA bf16 projections -> per-wave node attention.
// Interleaved per-node layouts:
//   qab[n][128] fp32  = [q_alpha | q_beta]
//   kab[n][128] bf16  = [k_alpha | k_beta]
//   vtx[n][128] bf16  = [v_t     | v_x   ]
// ---------------------------------------------------------------------------

#define D 64
#define CAP 96
#define NINF -3.0e38f
typedef unsigned short ushortT;
typedef unsigned long long ull;

typedef __attribute__((ext_vector_type(8))) short bf16x8;
typedef __attribute__((ext_vector_type(4))) float f32x4;

__device__ __forceinline__ float b2f(ushortT h) {
  return __uint_as_float(((unsigned)h) << 16);
}
__device__ __forceinline__ float b2f_lo(unsigned u) {
  return __uint_as_float(u << 16);
}
__device__ __forceinline__ float b2f_hi(unsigned u) {
  return __uint_as_float(u & 0xffff0000u);
}
__device__ __forceinline__ ushortT f2b(float f) {
  unsigned u = __float_as_uint(f);
  u += 0x7fffu + ((u >> 16) & 1u);
  return (ushortT)(u >> 16);
}

// inline edge dtype detection: first 64 u64 words; any >= nNodes -> int32
__device__ __forceinline__ bool wave_is64(const ull* __restrict__ ei, ull nNodes) {
  ull v = ei[threadIdx.x & 63];
  return __ballot(v >= nNodes) == 0ull;
}

// --- CSR build -------------------------------------------------------------
// Pass 1: histogram rows AND record each edge's rank within its row
// (atomicAdd's return value). Scatter then needs no atomics.
__global__ void edge_rank(const void* __restrict__ ei, int* __restrict__ deg,
                          int* __restrict__ rank, int E, ull nNodes) {
  const bool is64 = wave_is64((const ull*)ei, nNodes);
  int base = (blockIdx.x * blockDim.x + threadIdx.x) << 2;
  if (base >= E) return;
  int m = E - base; if (m > 4) m = 4;
  if (is64) {
    const long long* p = (const long long*)ei;
    for (int j = 0; j < m; ++j) {
      int r = (int)p[base + j];
      rank[base + j] = atomicAdd(&deg[r], 1);
    }
  } else {
    const int* p = (const int*)ei;
    for (int j = 0; j < m; ++j) {
      int r = p[base + j];
      rank[base + j] = atomicAdd(&deg[r], 1);
    }
  }
}

__global__ void scan_block_sums(const int* __restrict__ deg, int* __restrict__ bsum, int N) {
  __shared__ int sdata[256];
  int i = blockIdx.x * 256 + threadIdx.x;
  sdata[threadIdx.x] = (i < N) ? deg[i] : 0;
  __syncthreads();
  for (int s = 128; s > 0; s >>= 1) {
    if (threadIdx.x < s) sdata[threadIdx.x] += sdata[threadIdx.x + s];
    __syncthreads();
  }
  if (threadIdx.x == 0) bsum[blockIdx.x] = sdata[0];
}

__global__ void scan_exclusive_small(int* __restrict__ bsum, int nB) {
  __shared__ int sdata[256];
  int t = threadIdx.x;
  int v = (t < nB) ? bsum[t] : 0;
  sdata[t] = v;
  __syncthreads();
  for (int off = 1; off < 256; off <<= 1) {
    int add = (t >= off) ? sdata[t - off] : 0;
    __syncthreads();
    sdata[t] += add;
    __syncthreads();
  }
  if (t < nB) bsum[t] = sdata[t] - v;
}

__global__ void scan_finalize(const int* __restrict__ deg, const int* __restrict__ bsum,
                              int* __restrict__ offs, int N, int E) {
  __shared__ int sdata[256];
  int t = threadIdx.x;
  int i = blockIdx.x * 256 + t;
  int v = (i < N) ? deg[i] : 0;
  sdata[t] = v;
  __syncthreads();
  for (int off = 1; off < 256; off <<= 1) {
    int add = (t >= off) ? sdata[t - off] : 0;
    __syncthreads();
    sdata[t] += add;
    __syncthreads();
  }
  int excl = sdata[t] - v + bsum[blockIdx.x];
  if (i < N) offs[i] = excl;
  if (blockIdx.x == 0 && t == 0) offs[N] = E;
}

// atomic-free scatter: pos = offs[row] + rank[e]
__global__ void scatter_edges(const void* __restrict__ ei, const int* __restrict__ offs,
                              const int* __restrict__ rank, int* __restrict__ ecol,
                              int E, ull nNodes) {
  const bool is64 = wave_is64((const ull*)ei, nNodes);
  int base = (blockIdx.x * blockDim.x + threadIdx.x) << 2;
  if (base >= E) return;
  int m = E - base; if (m > 4) m = 4;
  if (is64) {
    const long long* p = (const long long*)ei;
    for (int j = 0; j < m; ++j) {
      int r = (int)p[base + j];
      int c = (int)p[(long long)E + base + j];
      ecol[offs[r] + rank[base + j]] = c;
    }
  } else {
    const int* p = (const int*)ei;
    for (int j = 0; j < m; ++j) {
      int r = p[base + j];
      int c = p[E + base + j];
      ecol[offs[r] + rank[base + j]] = c;
    }
  }
}

// --- projections: MFMA bf16 GEMM, one kernel, 4 jobs -----------------------
// Tile: 128 nodes x 64 outs per block (4 waves, each 32 nodes x 64 outs).
// X fp32 -> bf16 in-register during LDS staging; fp32 MFMA accumulate;
// bias added in fp32 epilogue. LDS rows padded to 72 ushorts (16B-aligned,
// balanced bank groups for the b128 fragment reads).
// Jobs: 0: t_tgt@QaW.T+b -> qab[:,0:64)   1: x_tgt@QbW.T+b -> qab[:,64:128)
//       2: t_src -> kab[:,0:64)(+b), vtx[:,0:64)
//       3: x_src -> kab[:,64:128)(+b), vtx[:,64:128)
#define AROW 72

__global__ __launch_bounds__(256) void proj_mfma(
    const float* __restrict__ t_tgt, const float* __restrict__ x_tgt,
    const float* __restrict__ t_src, const float* __restrict__ x_src,
    const float* __restrict__ QaW, const float* __restrict__ Qab_,
    const float* __restrict__ QbW, const float* __restrict__ Qbb,
    const float* __restrict__ KaW, const float* __restrict__ Kab_,
    const float* __restrict__ Wt,
    const float* __restrict__ KbW, const float* __restrict__ Kbb,
    const float* __restrict__ Wx,
    float* __restrict__ qab, ushortT* __restrict__ kab, ushortT* __restrict__ vtx,
    int nNodes, int bpj) {
  __shared__ ushortT As[128 * AROW];
  __shared__ ushortT W0s[64 * AROW];
  __shared__ ushortT W1s[64 * AROW];
  const int job = blockIdx.x / bpj;
  const int jb = blockIdx.x % bpj;
  const float *X, *W0, *B0, *W1 = nullptr;
  switch (job) {
    case 0: X = t_tgt; W0 = QaW; B0 = Qab_; break;
    case 1: X = x_tgt; W0 = QbW; B0 = Qbb; break;
    case 2: X = t_src; W0 = KaW; B0 = Kab_; W1 = Wt; break;
    default: X = x_src; W0 = KbW; B0 = Kbb; W1 = Wx; break;
  }
  const bool dual = (job >= 2);
  const int half = (job & 1) ? 64 : 0;
  const int tid = threadIdx.x;
  const int base = jb * 128;

  // stage X tile (128 x 64 fp32 -> bf16)
#pragma unroll
  for (int r = 0; r < 8; ++r) {
    int idx = tid + 256 * r;           // 0..2047
    int row = idx >> 4, k4 = idx & 15; // row 0..127, k4 0..15
    int gnode = base + row;
    float4 v = make_float4(0.f, 0.f, 0.f, 0.f);
    if (gnode < nNodes) v = *(const float4*)(X + (size_t)gnode * D + k4 * 4);
    ushort4 h;
    h.x = f2b(v.x); h.y = f2b(v.y); h.z = f2b(v.z); h.w = f2b(v.w);
    *(ushort4*)&As[row * AROW + k4 * 4] = h;
  }
  // stage W0 (64 x 64)
#pragma unroll
  for (int r = 0; r < 4; ++r) {
    int idx = tid + 256 * r;           // 0..1023
    int row = idx >> 4, k4 = idx & 15;
    float4 v = *(const float4*)(W0 + row * D + k4 * 4);
    ushort4 h;
    h.x = f2b(v.x); h.y = f2b(v.y); h.z = f2b(v.z); h.w = f2b(v.w);
    *(ushort4*)&W0s[row * AROW + k4 * 4] = h;
  }
  if (dual) {
#pragma unroll
    for (int r = 0; r < 4; ++r) {
      int idx = tid + 256 * r;
      int row = idx >> 4, k4 = idx & 15;
      float4 v = *(const float4*)(W1 + row * D + k4 * 4);
      ushort4 h;
      h.x = f2b(v.x); h.y = f2b(v.y); h.z = f2b(v.z); h.w = f2b(v.w);
      *(ushort4*)&W1s[row * AROW + k4 * 4] = h;
    }
  }
  __syncthreads();

  const int lane = tid & 63;
  const int wid = tid >> 6;
  const int m16 = lane & 15;
  const int quad = lane >> 4;

  f32x4 acc0[2][4], acc1[2][4];
#pragma unroll
  for (int mt = 0; mt < 2; ++mt)
#pragma unroll
    for (int nt = 0; nt < 4; ++nt) {
      acc0[mt][nt] = (f32x4){0.f, 0.f, 0.f, 0.f};
      acc1[mt][nt] = (f32x4){0.f, 0.f, 0.f, 0.f};
    }

#pragma unroll
  for (int ko = 0; ko < 2; ++ko) {
    const int koff = ko * 32 + quad * 8;
    bf16x8 a[2];
#pragma unroll
    for (int mt = 0; mt < 2; ++mt)
      a[mt] = *(const bf16x8*)&As[(wid * 32 + mt * 16 + m16) * AROW + koff];
#pragma unroll
    for (int nt = 0; nt < 4; ++nt) {
      bf16x8 b = *(const bf16x8*)&W0s[(nt * 16 + m16) * AROW + koff];
#pragma unroll
      for (int mt = 0; mt < 2; ++mt)
        acc0[mt][nt] = __builtin_amdgcn_mfma_f32_16x16x32_bf16(
            a[mt], b, acc0[mt][nt], 0, 0, 0);
    }
    if (dual) {
#pragma unroll
      for (int nt = 0; nt < 4; ++nt) {
        bf16x8 b = *(const bf16x8*)&W1s[(nt * 16 + m16) * AROW + koff];
#pragma unroll
        for (int mt = 0; mt < 2; ++mt)
          acc1[mt][nt] = __builtin_amdgcn_mfma_f32_16x16x32_bf16(
              a[mt], b, acc1[mt][nt], 0, 0, 0);
      }
    }
  }

  // epilogue: D layout col=lane&15 (out), row=quad*4+reg (node within 16)
  float bias[4];
#pragma unroll
  for (int nt = 0; nt < 4; ++nt) bias[nt] = B0[nt * 16 + m16];
#pragma unroll
  for (int mt = 0; mt < 2; ++mt) {
#pragma unroll
    for (int reg = 0; reg < 4; ++reg) {
      int node = base + wid * 32 + mt * 16 + quad * 4 + reg;
      if (node < nNodes) {
        if (!dual) {
          float* dst = qab + (size_t)node * 128 + half;
#pragma unroll
          for (int nt = 0; nt < 4; ++nt)
            dst[nt * 16 + m16] = acc0[mt][nt][reg] + bias[nt];
        } else {
          ushortT* dk = kab + (size_t)node * 128 + half;
          ushortT* dv = vtx + (size_t)node * 128 + half;
#pragma unroll
          for (int nt = 0; nt < 4; ++nt) {
            dk[nt * 16 + m16] = f2b(acc0[mt][nt][reg] + bias[nt]);
            dv[nt * 16 + m16] = f2b(acc1[mt][nt][reg]);
          }
        }
      }
    }
  }
}

// --- per-node attention + aggregation, one wave per destination node -------
__global__ __launch_bounds__(256) void node_attn(
    const float* __restrict__ qab, const ushortT* __restrict__ kab,
    const ushortT* __restrict__ vtx,
    const int* __restrict__ offs, const int* __restrict__ ecol,
    float* __restrict__ out_x, float* __restrict__ out_t, int nNodes) {
  __shared__ float s_wa[4][CAP];
  __shared__ float s_wb[4][CAP];
  __shared__ int s_c[4][CAP];
  const int lane = threadIdx.x & 63;
  const int wid = threadIdx.x >> 6;
  const int sub = lane >> 4;   // edge within chunk of 4
  const int sl = lane & 15;    // sublane: 0-7 -> alpha dot, 8-15 -> beta dot
  const int gw = (blockIdx.x * blockDim.x + threadIdx.x) >> 6;
  const int nw = (gridDim.x * blockDim.x) >> 6;
  const float scale = 0.125f;

  for (int n = gw; n < nNodes; n += nw) {
    const int s = offs[n], e = offs[n + 1], deg = e - s;
    const size_t nb = (size_t)n * D;
    if (deg == 0) {
      out_x[nb + lane] = 0.f;
      out_t[nb + lane] = 0.f;
      continue;
    }
    float acc_t = 0.f, acc_x = 0.f;
    if (deg <= CAP) {
      const float4 q0 = *(const float4*)(qab + (size_t)n * 128 + sl * 8);
      const float4 q1 = *(const float4*)(qab + (size_t)n * 128 + sl * 8 + 4);
      for (int i = 0; i < deg; i += 4) {
        const int idx = i + sub;
        const bool act = idx < deg;
        const int c = ecol[s + (act ? idx : 0)];
        const uint4 u = *(const uint4*)(kab + (size_t)c * 128 + sl * 8);
        float v = q0.x * b2f_lo(u.x);
        v = fmaf(q0.y, b2f_hi(u.x), v);
        v = fmaf(q0.z, b2f_lo(u.y), v);
        v = fmaf(q0.w, b2f_hi(u.y), v);
        v = fmaf(q1.x, b2f_lo(u.z), v);
        v = fmaf(q1.y, b2f_hi(u.z), v);
        v = fmaf(q1.z, b2f_lo(u.w), v);
        v = fmaf(q1.w, b2f_hi(u.w), v);
#pragma unroll
        for (int off = 1; off < 8; off <<= 1) v += __shfl_xor(v, off);
        if (act) {
          if (sl == 0) { s_wa[wid][idx] = v * scale; s_c[wid][idx] = c; }
          if (sl == 8) s_wb[wid][idx] = v * scale;
        }
      }
      float sa = (lane < deg) ? s_wa[wid][lane] : NINF;
      float sb = (lane < deg) ? s_wb[wid][lane] : NINF;
      float ma, mb, da, db;
      if (deg <= 64) {
        ma = sa; mb = sb;
#pragma unroll
        for (int off = 1; off < 64; off <<= 1) {
          ma = fmaxf(ma, __shfl_xor(ma, off));
          mb = fmaxf(mb, __shfl_xor(mb, off));
        }
        float ea = __expf(sa - ma), eb = __expf(sb - mb);
        da = ea; db = eb;
#pragma unroll
        for (int off = 1; off < 64; off <<= 1) {
          da += __shfl_xor(da, off);
          db += __shfl_xor(db, off);
        }
        const float ia = 1.0f / da, ib = 1.0f / db;
        if (lane < deg) { s_wa[wid][lane] = ea * ia; s_wb[wid][lane] = eb * ib; }
      } else {
        float sa1 = (lane + 64 < deg) ? s_wa[wid][lane + 64] : NINF;
        float sb1 = (lane + 64 < deg) ? s_wb[wid][lane + 64] : NINF;
        ma = fmaxf(sa, sa1); mb = fmaxf(sb, sb1);
#pragma unroll
        for (int off = 1; off < 64; off <<= 1) {
          ma = fmaxf(ma, __shfl_xor(ma, off));
          mb = fmaxf(mb, __shfl_xor(mb, off));
        }
        float ea0 = __expf(sa - ma), ea1 = __expf(sa1 - ma);
        float eb0 = __expf(sb - mb), eb1 = __expf(sb1 - mb);
        da = ea0 + ea1; db = eb0 + eb1;
#pragma unroll
        for (int off = 1; off < 64; off <<= 1) {
          da += __shfl_xor(da, off);
          db += __shfl_xor(db, off);
        }
        const float ia = 1.0f / da, ib = 1.0f / db;
        if (lane < deg) { s_wa[wid][lane] = ea0 * ia; s_wb[wid][lane] = eb0 * ib; }
        if (lane + 64 < deg) { s_wa[wid][lane + 64] = ea1 * ia; s_wb[wid][lane + 64] = eb1 * ib; }
      }
      int i = 0;
      for (; i + 2 <= deg; i += 2) {
        const int c0 = s_c[wid][i], c1 = s_c[wid][i + 1];
        const ushortT* b0 = vtx + (size_t)c0 * 128;
        const ushortT* b1 = vtx + (size_t)c1 * 128;
        float t0 = b2f(b0[lane]), x0 = b2f(b0[lane + 64]);
        float t1 = b2f(b1[lane]), x1 = b2f(b1[lane + 64]);
        float wa0 = s_wa[wid][i], wa1 = s_wa[wid][i + 1];
        float wb0 = s_wb[wid][i], wb1 = s_wb[wid][i + 1];
        acc_t = fmaf(wa0, t0, acc_t);
        acc_t = fmaf(wa1, t1, acc_t);
        acc_x = fmaf(wb0, x0, acc_x);
        acc_x = fmaf(wb1, x1, acc_x);
      }
      if (i < deg) {
        const int c0 = s_c[wid][i];
        const ushortT* b0 = vtx + (size_t)c0 * 128;
        acc_t = fmaf(s_wa[wid][i], b2f(b0[lane]), acc_t);
        acc_x = fmaf(s_wb[wid][i], b2f(b0[lane + 64]), acc_x);
      }
    } else {
      const float qla = qab[(size_t)n * 128 + lane];
      const float qlb = qab[(size_t)n * 128 + 64 + lane];
      float ma = NINF, mb = NINF, da = 0.f, db = 0.f;
      for (int i = s; i < e; ++i) {
        int c = ecol[i];
        float va = qla * b2f(kab[(size_t)c * 128 + lane]);
        float vb = qlb * b2f(kab[(size_t)c * 128 + 64 + lane]);
#pragma unroll
        for (int off = 1; off < 64; off <<= 1) {
          va += __shfl_xor(va, off);
          vb += __shfl_xor(vb, off);
        }
        va *= scale; vb *= scale;
        float na = fmaxf(ma, va);
        da = da * __expf(ma - na) + __expf(va - na);
        ma = na;
        float nb2 = fmaxf(mb, vb);
        db = db * __expf(mb - nb2) + __expf(vb - nb2);
        mb = nb2;
      }
      const float ia = 1.0f / da, ib = 1.0f / db;
      for (int i = s; i < e; ++i) {
        int c = ecol[i];
        float va = qla * b2f(kab[(size_t)c * 128 + lane]);
        float vb = qlb * b2f(kab[(size_t)c * 128 + 64 + lane]);
#pragma unroll
        for (int off = 1; off < 64; off <<= 1) {
          va += __shfl_xor(va, off);
          vb += __shfl_xor(vb, off);
        }
        float al = __expf(va * scale - ma) * ia;
        float be = __expf(vb * scale - mb) * ib;
        const ushortT* b0 = vtx + (size_t)c * 128;
        acc_t = fmaf(al, b2f(b0[lane]), acc_t);
        acc_x = fmaf(be, b2f(b0[lane + 64]), acc_x);
      }
    }
    out_t[nb + lane] = acc_t;
    out_x[nb + lane] = acc_x;
  }
}

// ---------------------------------------------------------------------------
extern "C" void kernel_launch(void* const* d_in, const int* in_sizes, int n_in,
                              void* d_out, int out_size, void* d_ws, size_t ws_size,
                              hipStream_t stream) {
  const float* x_src = (const float*)d_in[0];
  const float* x_tgt = (const float*)d_in[1];
  const float* t_src = (const float*)d_in[2];
  const float* t_tgt = (const float*)d_in[3];
  const void* edge_index = d_in[4];
  const float* W_x = (const float*)d_in[5];
  const float* W_t = (const float*)d_in[6];
  const float* Ka_W = (const float*)d_in[7];
  const float* Ka_b = (const float*)d_in[8];
  const float* Qa_W = (const float*)d_in[9];
  const float* Qa_b = (const float*)d_in[10];
  const float* Kb_W = (const float*)d_in[11];
  const float* Kb_b = (const float*)d_in[12];
  const float* Qb_W = (const float*)d_in[13];
  const float* Qb_b = (const float*)d_in[14];

  const int N = in_sizes[0] / D;
  const int E = in_sizes[4] / 2;
  const int nB = (N + 255) / 256;  // <= 256

  char* ws = (char*)d_ws;
  size_t ofs = 0;
  auto carve = [&](size_t bytes) {
    size_t p = ofs;
    ofs += (bytes + 255) & ~(size_t)255;
    return p;
  };
  float* qab = (float*)(ws + carve((size_t)N * 128 * 4));
  ushortT* kab = (ushortT*)(ws + carve((size_t)N * 128 * 2));
  ushortT* vtx = (ushortT*)(ws + carve((size_t)N * 128 * 2));
  int* offs = (int*)(ws + carve(((size_t)N + 1) * 4));
  int* deg = (int*)(ws + carve((size_t)N * 4));
  int* bsum = (int*)(ws + carve((size_t)nB * 4));
  int* rank = (int*)(ws + carve((size_t)E * 4));
  int* ecol = (int*)(ws + carve((size_t)E * 4));
  (void)ws_size;

  float* out_x = (float*)d_out;
  float* out_t = out_x + (size_t)N * D;

  const int e4Blocks = ((E + 3) / 4 + 255) / 256;

  hipMemsetAsync(deg, 0, (size_t)N * 4, stream);
  edge_rank<<<e4Blocks, 256, 0, stream>>>(edge_index, deg, rank, E, (ull)N);
  scan_block_sums<<<nB, 256, 0, stream>>>(deg, bsum, N);
  scan_exclusive_small<<<1, 256, 0, stream>>>(bsum, nB);
  scan_finalize<<<nB, 256, 0, stream>>>(deg, bsum, offs, N, E);
  scatter_edges<<<e4Blocks, 256, 0, stream>>>(edge_index, offs, rank, ecol, E, (ull)N);

  const int bpj = (N + 127) / 128;
  proj_mfma<<<4 * bpj, 256, 0, stream>>>(t_tgt, x_tgt, t_src, x_src,
                                         Qa_W, Qa_b, Qb_W, Qb_b,
                                         Ka_W, Ka_b, W_t,
                                         Kb_W, Kb_b, W_x,
                                         qab, kab, vtx, N, bpj);

  node_attn<<<(N + 3) / 4, 256, 0, stream>>>(qab, kab, vtx, offs, ecol,
                                             out_x, out_t, N);
}